// Round 2
// baseline (2993.245 us; speedup 1.0000x reference)
//
#include <hip/hip_runtime.h>
#include <math.h>

#define NTOK 16384   // 128 sequences * 128 steps

__device__ __forceinline__ float geluf(float x){
    return 0.5f*x*(1.0f+erff(x*0.70710678118654752f));
}
__device__ __forceinline__ float siluf(float x){
    return x/(1.0f+__expf(-x));
}
__device__ __forceinline__ float softplusf(float x){
    return (x>20.0f)? x : log1pf(__expf(x));
}

// ---------------------------------------------------------------------------
// conv2d 3x3 SAME, in [CI,128,128], w [CO,CI,3,3], out [CO,128,128]
// grid (2 wtiles, 8 htiles, ceil(CO/8)); block 256 = (ty16, tx16)
// each thread: 8 c_out x 4 w outputs
template<bool GELU_OUT>
__global__ __launch_bounds__(256) void conv3x3_kernel(
    const float* __restrict__ in, const float* __restrict__ wgt,
    const float* __restrict__ bias, float* __restrict__ out,
    int CI, int CO)
{
    __shared__ float tile[18][68];
    const int tx = threadIdx.x & 15;
    const int ty = threadIdx.x >> 4;
    const int w0 = blockIdx.x * 64;
    const int h0 = blockIdx.y * 16;
    const int cog = blockIdx.z * 8;

    float acc[8][4];
    #pragma unroll
    for (int i=0;i<8;i++){
        float b = (cog+i < CO) ? bias[cog+i] : 0.f;
        #pragma unroll
        for (int j=0;j<4;j++) acc[i][j] = b;
    }

    for (int ci=0; ci<CI; ci++){
        const float* inp = in + ci*16384;
        for (int e = threadIdx.x; e < 18*66; e += 256){
            int r = e/66, cc = e - r*66;
            int hh = h0 - 1 + r, ww = w0 - 1 + cc;
            float v = 0.f;
            if ((unsigned)hh < 128u && (unsigned)ww < 128u) v = inp[hh*128+ww];
            tile[r][cc] = v;
        }
        __syncthreads();
        float rin[3][8];
        #pragma unroll
        for (int r=0;r<3;r++){
            float4 a = *(const float4*)&tile[ty+r][tx*4];
            float4 b = *(const float4*)&tile[ty+r][tx*4+4];
            rin[r][0]=a.x; rin[r][1]=a.y; rin[r][2]=a.z; rin[r][3]=a.w;
            rin[r][4]=b.x; rin[r][5]=b.y; rin[r][6]=b.z; rin[r][7]=b.w;
        }
        #pragma unroll
        for (int co=0; co<8; co++){
            if (cog+co < CO) {
                const float* wp = wgt + ((cog+co)*CI + ci)*9;
                #pragma unroll
                for (int r=0;r<3;r++){
                    #pragma unroll
                    for (int dx=0;dx<3;dx++){
                        float wv = wp[r*3+dx];
                        #pragma unroll
                        for (int j=0;j<4;j++)
                            acc[co][j] = fmaf(wv, rin[r][j+dx], acc[co][j]);
                    }
                }
            }
        }
        __syncthreads();
    }
    const int h = h0 + ty;
    const int wbase = w0 + tx*4;
    #pragma unroll
    for (int co=0; co<8; co++){
        if (cog+co < CO){
            float t0 = acc[co][0], t1 = acc[co][1], t2 = acc[co][2], t3 = acc[co][3];
            if (GELU_OUT){ t0=geluf(t0); t1=geluf(t1); t2=geluf(t2); t3=geluf(t3); }
            *(float4*)&out[(cog+co)*16384 + h*128 + wbase] = make_float4(t0,t1,t2,t3);
        }
    }
}

// ---------------------------------------------------------------------------
// C[M,N] = A[M,K] * W[N,K]^T.  BM=128 BN=64 BK=16, 256 thr, 8x4 per thread.
// K multiple of 16, M multiple of 128, N multiple of 4 (masked to N).
__global__ __launch_bounds__(256) void gemm_kernel(
    const float* __restrict__ A, const float* __restrict__ W,
    float* __restrict__ C, int M, int N, int K)
{
    __shared__ float As[16][132];
    __shared__ float Ws[16][68];
    const int tid = threadIdx.x;
    const int tx = tid & 15;
    const int ty = tid >> 4;
    const int m0 = blockIdx.x * 128;
    const int n0 = blockIdx.y * 64;

    float acc[8][4] = {};

    const int arow  = tid >> 2;   // 0..63
    const int acol4 = tid & 3;    // k chunk

    for (int k0 = 0; k0 < K; k0 += 16){
        #pragma unroll
        for (int half=0; half<2; half++){
            int r = arow + half*64;
            float4 v = *(const float4*)&A[(size_t)(m0+r)*K + k0 + acol4*4];
            As[acol4*4+0][r] = v.x;
            As[acol4*4+1][r] = v.y;
            As[acol4*4+2][r] = v.z;
            As[acol4*4+3][r] = v.w;
        }
        {
            int r = arow;
            float4 v = make_float4(0.f,0.f,0.f,0.f);
            if (n0 + r < N) v = *(const float4*)&W[(size_t)(n0+r)*K + k0 + acol4*4];
            Ws[acol4*4+0][r] = v.x;
            Ws[acol4*4+1][r] = v.y;
            Ws[acol4*4+2][r] = v.z;
            Ws[acol4*4+3][r] = v.w;
        }
        __syncthreads();
        #pragma unroll
        for (int k=0;k<16;k++){
            float4 a0 = *(const float4*)&As[k][ty*8];
            float4 a1 = *(const float4*)&As[k][ty*8+4];
            float4 bv = *(const float4*)&Ws[k][tx*4];
            float a[8] = {a0.x,a0.y,a0.z,a0.w,a1.x,a1.y,a1.z,a1.w};
            float b[4] = {bv.x,bv.y,bv.z,bv.w};
            #pragma unroll
            for (int i=0;i<8;i++)
                #pragma unroll
                for (int j=0;j<4;j++)
                    acc[i][j] = fmaf(a[i], b[j], acc[i][j]);
        }
        __syncthreads();
    }
    #pragma unroll
    for (int i=0;i<8;i++){
        int m = m0 + ty*8 + i;
        int n = n0 + tx*4;
        if (n < N)
            *(float4*)&C[(size_t)m*N + n] = make_float4(acc[i][0],acc[i][1],acc[i][2],acc[i][3]);
    }
}

// ---------------------------------------------------------------------------
// depthwise causal conv1d (k=4) + silu.  xz [NTOK,512] (xs = cols 0..255)
__global__ __launch_bounds__(256) void conv1d_silu_kernel(
    const float* __restrict__ xz, const float* __restrict__ cw,
    const float* __restrict__ cb, float* __restrict__ U)
{
    const int m = blockIdx.x;
    const int d = threadIdx.x;
    const int t = m & 127;
    float4 w4 = *(const float4*)&cw[d*4];
    float wj[4] = {w4.x, w4.y, w4.z, w4.w};
    float s = cb[d];
    #pragma unroll
    for (int j=0;j<4;j++){
        int tt = t - 3 + j;
        if (tt >= 0) s = fmaf(wj[j], xz[(size_t)(m - 3 + j)*512 + d], s);
    }
    U[(size_t)m*256 + d] = siluf(s);
}

// ---------------------------------------------------------------------------
// delta = softplus(proj[:, :8] @ dt_w.T + dt_b); written into xz cols [0,256)
__global__ __launch_bounds__(256) void dt_softplus_kernel(
    const float* __restrict__ proj, const float* __restrict__ dtw,
    const float* __restrict__ dtb, float* xzd)
{
    const int m = blockIdx.x;
    const int d = threadIdx.x;
    const float* p = proj + (size_t)m*40;
    float4 w0 = *(const float4*)&dtw[d*8];
    float4 w1 = *(const float4*)&dtw[d*8+4];
    float s = dtb[d];
    s = fmaf(p[0],w0.x, fmaf(p[1],w0.y, fmaf(p[2],w0.z, fmaf(p[3],w0.w, s))));
    s = fmaf(p[4],w1.x, fmaf(p[5],w1.y, fmaf(p[6],w1.z, fmaf(p[7],w1.w, s))));
    xzd[(size_t)m*512 + d] = softplusf(s);
}

// ---------------------------------------------------------------------------
// selective scan. one thread per (b,d). delta read from xz cols[0,256),
// ys written in place over it. B/C rows are wave-uniform (s_loads).
__global__ __launch_bounds__(64) void scan_kernel(
    float* xzd, const float* __restrict__ u,
    const float* __restrict__ proj, const float* __restrict__ Alog)
{
    const int b = blockIdx.y;
    const int d = blockIdx.x*64 + threadIdx.x;
    float A[16], h[16];
    #pragma unroll
    for (int s=0;s<16;s++){ A[s] = -__expf(Alog[d*16+s]); h[s] = 0.f; }

    int m = b*128;
    float dv = xzd[(size_t)m*512+d];
    float uv = u[(size_t)m*256+d];
    float Bc[16], Cc[16];
    #pragma unroll
    for (int s=0;s<16;s++){ Bc[s] = proj[(size_t)m*40+8+s]; Cc[s] = proj[(size_t)m*40+24+s]; }

    for (int t=0;t<128;t++){
        const int mn = m+1;
        float dv_n=0.f, uv_n=0.f, Bn[16], Cn[16];
        #pragma unroll
        for (int s=0;s<16;s++){ Bn[s]=0.f; Cn[s]=0.f; }
        if (t<127){
            dv_n = xzd[(size_t)mn*512+d];
            uv_n = u[(size_t)mn*256+d];
            #pragma unroll
            for (int s=0;s<16;s++){ Bn[s]=proj[(size_t)mn*40+8+s]; Cn[s]=proj[(size_t)mn*40+24+s]; }
        }
        float du = dv*uv;
        float y = 0.f;
        #pragma unroll
        for (int s=0;s<16;s++){
            float dA = __expf(dv*A[s]);
            h[s] = fmaf(dA, h[s], du*Bc[s]);
            y = fmaf(h[s], Cc[s], y);
        }
        xzd[(size_t)m*512+d] = y;
        m = mn; dv = dv_n; uv = uv_n;
        #pragma unroll
        for (int s=0;s<16;s++){ Bc[s]=Bn[s]; Cc[s]=Cn[s]; }
    }
}

// ---------------------------------------------------------------------------
// y = (ys + u*D) * silu(z); ys in xz cols[0,256), z in cols[256,512); into U
__global__ __launch_bounds__(256) void ycombine_kernel(
    const float* __restrict__ xz, const float* __restrict__ Dp, float* u)
{
    const int m = blockIdx.x;
    const int d = threadIdx.x;
    float uv = u[(size_t)m*256+d];
    float y = xz[(size_t)m*512+d] + uv * Dp[d];
    float z = xz[(size_t)m*512+256+d];
    u[(size_t)m*256+d] = y * siluf(z);
}

// ---------------------------------------------------------------------------
// feats[c,h,w] -> out[w*ows + h*ohs + c]   (per-h 128x128 transpose)
__global__ __launch_bounds__(256) void transpose_cw_kernel(
    const float* __restrict__ feats, float* __restrict__ out,
    int ows, int ohs)
{
    __shared__ float tile[32][33];
    const int h = blockIdx.z;
    const int c0 = blockIdx.y*32, w0 = blockIdx.x*32;
    const int lx = threadIdx.x & 31, ly = threadIdx.x >> 5;
    #pragma unroll
    for (int i=0;i<4;i++){
        int c = c0 + ly + i*8;
        tile[ly+i*8][lx] = feats[(size_t)c*16384 + h*128 + w0 + lx];
    }
    __syncthreads();
    #pragma unroll
    for (int i=0;i<4;i++){
        int w = w0 + ly + i*8;
        out[(size_t)w*ows + (size_t)h*ohs + c0 + lx] = tile[lx][ly+i*8];
    }
}

// FH[c,h,w] = XH[w,h,c] + XW[h,w,c]
__global__ __launch_bounds__(256) void fuse_transpose_kernel(
    const float* __restrict__ XH, const float* __restrict__ XW,
    float* __restrict__ FH)
{
    __shared__ float tile[32][33];
    const int h = blockIdx.z;
    const int c0 = blockIdx.y*32, w0 = blockIdx.x*32;
    const int lx = threadIdx.x & 31, ly = threadIdx.x >> 5;
    #pragma unroll
    for (int i=0;i<4;i++){
        int w = w0 + ly + i*8;
        float v = XH[(size_t)w*16384 + h*128 + c0 + lx]
                + XW[(size_t)h*16384 + w*128 + c0 + lx];
        tile[ly+i*8][lx] = v;   // [w_local][c_local]
    }
    __syncthreads();
    #pragma unroll
    for (int i=0;i<4;i++){
        int c = c0 + ly + i*8;
        FH[(size_t)c*16384 + h*128 + w0 + lx] = tile[lx][ly+i*8];
    }
}

// ---------------------------------------------------------------------------
extern "C" void kernel_launch(void* const* d_in, const int* in_sizes, int n_in,
                              void* d_out, int out_size, void* d_ws, size_t ws_size,
                              hipStream_t stream)
{
    const float* x        = (const float*)d_in[0];
    const float* enc1_w   = (const float*)d_in[1];
    const float* enc1_b   = (const float*)d_in[2];
    const float* enc2_w   = (const float*)d_in[3];
    const float* enc2_b   = (const float*)d_in[4];
    const float* m_in_w   = (const float*)d_in[5];
    const float* m_conv_w = (const float*)d_in[6];
    const float* m_conv_b = (const float*)d_in[7];
    const float* m_xproj_w= (const float*)d_in[8];
    const float* m_dt_w   = (const float*)d_in[9];
    const float* m_dt_b   = (const float*)d_in[10];
    const float* m_Alog   = (const float*)d_in[11];
    const float* m_D      = (const float*)d_in[12];
    const float* m_out_w  = (const float*)d_in[13];
    const float* fus_w    = (const float*)d_in[14];
    const float* fus_b    = (const float*)d_in[15];
    const float* pred1_w  = (const float*)d_in[16];
    const float* pred1_b  = (const float*)d_in[17];
    const float* pred2_w  = (const float*)d_in[18];
    const float* pred2_b  = (const float*)d_in[19];
    float* out = (float*)d_out;

    float* ws    = (float*)d_ws;
    float* FEATS = ws;                         // 2M floats
    float* XH    = ws +  2u*1024*1024;         // 2M
    float* XW    = ws +  4u*1024*1024;         // 2M
    float* XZ    = ws +  6u*1024*1024;         // 8M  [NTOK,512]
    float* U     = ws + 14u*1024*1024;         // 4M  [NTOK,256]
    float* PROJ  = ws + 18u*1024*1024;         // 640K [NTOK,40]
    // liveness-based aliases within XZ (dead outside the mamba stacks):
    float* T0 = XZ;                  // conv1 output
    float* FH = XZ;                  // feats_h + feats_w
    float* G1 = XZ + 2u*1024*1024;   // fus conv output
    float* G2 = XZ + 4u*1024*1024;   // pred1 output

    const dim3 cgrid(2, 8, 16);

    // encoder
    conv3x3_kernel<true ><<<cgrid, 256, 0, stream>>>(x,  enc1_w, enc1_b, T0,    1,   128);
    conv3x3_kernel<false><<<cgrid, 256, 0, stream>>>(T0, enc2_w, enc2_b, FEATS, 128, 128);

    // layouts for the two scan directions
    transpose_cw_kernel<<<dim3(4,4,128), 256, 0, stream>>>(FEATS, XH, 16384, 128); // [w,h,c]
    transpose_cw_kernel<<<dim3(4,4,128), 256, 0, stream>>>(FEATS, XW, 128, 16384); // [h,w,c]

    for (int pass = 0; pass < 2; pass++){
        float* Xact = pass ? XW : XH;
        for (int l = 0; l < 3; l++){
            gemm_kernel<<<dim3(128,8), 256, 0, stream>>>(Xact, m_in_w + (size_t)l*512*128, XZ, NTOK, 512, 128);
            conv1d_silu_kernel<<<NTOK, 256, 0, stream>>>(XZ, m_conv_w + (size_t)l*256*4, m_conv_b + (size_t)l*256, U);
            gemm_kernel<<<dim3(128,1), 256, 0, stream>>>(U, m_xproj_w + (size_t)l*40*256, PROJ, NTOK, 40, 256);
            dt_softplus_kernel<<<NTOK, 256, 0, stream>>>(PROJ, m_dt_w + (size_t)l*256*8, m_dt_b + (size_t)l*256, XZ);
            scan_kernel<<<dim3(4,128), 64, 0, stream>>>(XZ, U, PROJ, m_Alog + (size_t)l*256*16);
            ycombine_kernel<<<NTOK, 256, 0, stream>>>(XZ, m_D + (size_t)l*256, U);
            gemm_kernel<<<dim3(128,2), 256, 0, stream>>>(U, m_out_w + (size_t)l*128*256, Xact, NTOK, 128, 256);
        }
    }

    fuse_transpose_kernel<<<dim3(4,4,128), 256, 0, stream>>>(XH, XW, FH);

    // decoder
    conv3x3_kernel<false><<<cgrid,        256, 0, stream>>>(FH, fus_w,   fus_b,   G1, 128, 128);
    conv3x3_kernel<true ><<<cgrid,        256, 0, stream>>>(G1, pred1_w, pred1_b, G2, 128, 128);
    conv3x3_kernel<false><<<dim3(2,8,1),  256, 0, stream>>>(G2, pred2_w, pred2_b, out, 128, 1);
}

// Round 4
// 1932.907 us; speedup vs baseline: 1.5486x; 1.5486x over previous
//
#include <hip/hip_runtime.h>
#include <math.h>

#define NTOK 16384   // 128 sequences * 128 steps

__device__ __forceinline__ float geluf(float x){
    return 0.5f*x*(1.0f+erff(x*0.70710678118654752f));
}
__device__ __forceinline__ float siluf(float x){
    return x/(1.0f+__expf(-x));
}
__device__ __forceinline__ float softplusf(float x){
    return (x>20.0f)? x : log1pf(__expf(x));
}

// ---------------------------------------------------------------------------
// ORIGINAL conv (kept only for enc1, CI=1 -> single ci iteration, cheap)
template<bool GELU_OUT>
__global__ __launch_bounds__(256) void conv3x3_kernel(
    const float* __restrict__ in, const float* __restrict__ wgt,
    const float* __restrict__ bias, float* __restrict__ out,
    int CI, int CO)
{
    __shared__ float tile[18][68];
    const int tx = threadIdx.x & 15;
    const int ty = threadIdx.x >> 4;
    const int w0 = blockIdx.x * 64;
    const int h0 = blockIdx.y * 16;
    const int cog = blockIdx.z * 8;

    float acc[8][4];
    #pragma unroll
    for (int i=0;i<8;i++){
        float b = (cog+i < CO) ? bias[cog+i] : 0.f;
        #pragma unroll
        for (int j=0;j<4;j++) acc[i][j] = b;
    }

    for (int ci=0; ci<CI; ci++){
        const float* inp = in + ci*16384;
        for (int e = threadIdx.x; e < 18*66; e += 256){
            int r = e/66, cc = e - r*66;
            int hh = h0 - 1 + r, ww = w0 - 1 + cc;
            float v = 0.f;
            if ((unsigned)hh < 128u && (unsigned)ww < 128u) v = inp[hh*128+ww];
            tile[r][cc] = v;
        }
        __syncthreads();
        float rin[3][8];
        #pragma unroll
        for (int r=0;r<3;r++){
            float4 a = *(const float4*)&tile[ty+r][tx*4];
            float4 b = *(const float4*)&tile[ty+r][tx*4+4];
            rin[r][0]=a.x; rin[r][1]=a.y; rin[r][2]=a.z; rin[r][3]=a.w;
            rin[r][4]=b.x; rin[r][5]=b.y; rin[r][6]=b.z; rin[r][7]=b.w;
        }
        #pragma unroll
        for (int co=0; co<8; co++){
            if (cog+co < CO) {
                const float* wp = wgt + ((cog+co)*CI + ci)*9;
                #pragma unroll
                for (int r=0;r<3;r++){
                    #pragma unroll
                    for (int dx=0;dx<3;dx++){
                        float wv = wp[r*3+dx];
                        #pragma unroll
                        for (int j=0;j<4;j++)
                            acc[co][j] = fmaf(wv, rin[r][j+dx], acc[co][j]);
                    }
                }
            }
        }
        __syncthreads();
    }
    const int h = h0 + ty;
    const int wbase = w0 + tx*4;
    #pragma unroll
    for (int co=0; co<8; co++){
        if (cog+co < CO){
            float t0 = acc[co][0], t1 = acc[co][1], t2 = acc[co][2], t3 = acc[co][3];
            if (GELU_OUT){ t0=geluf(t0); t1=geluf(t1); t2=geluf(t2); t3=geluf(t3); }
            *(float4*)&out[(cog+co)*16384 + h*128 + wbase] = make_float4(t0,t1,t2,t3);
        }
    }
}

// ---------------------------------------------------------------------------
// NEW conv: CI multiple of 8, CO multiple of 8. grid (4,8,CO/8) = 512 blocks.
// block: 16h x 32w x 8co.  thread (wq 0..7, ty 0..15, ch 0..1): 4w x 4co.
// ci staged in chunks of 8; weights via wave-uniform scalar loads.
template<bool GELU_OUT>
__global__ __launch_bounds__(256) void conv3x3_rf_kernel(
    const float* __restrict__ in, const float* __restrict__ wgt,
    const float* __restrict__ bias, float* __restrict__ out,
    int CI)
{
    __shared__ float sbuf[8*18*40];
    const int wq = threadIdx.x & 7;
    const int ty = (threadIdx.x >> 3) & 15;
    const int ch4 = __builtin_amdgcn_readfirstlane((threadIdx.x >> 7) << 2); // 0 or 4
    const int w0 = blockIdx.x * 32;
    const int h0 = blockIdx.y * 16;
    const int cog8 = blockIdx.z * 8;

    float acc[4][4];
    #pragma unroll
    for (int i=0;i<4;i++){
        float b = bias[cog8 + ch4 + i];
        #pragma unroll
        for (int j=0;j<4;j++) acc[i][j] = b;
    }

    for (int cc0 = 0; cc0 < CI; cc0 += 8){
        // stage 8 channels: rows h0-1..h0+16 (18), cols w0-4..w0+35 (10 float4)
        for (int e = threadIdx.x; e < 1440; e += 256){
            int ci  = e / 180;
            int rem = e - ci*180;
            int r   = rem / 10;
            int c4  = rem - r*10;
            int hh  = h0 - 1 + r;
            int wwb = w0 - 4 + c4*4;
            float4 v = make_float4(0.f,0.f,0.f,0.f);
            if ((unsigned)hh < 128u && (unsigned)wwb < 128u)
                v = *(const float4*)&in[(size_t)(cc0+ci)*16384 + hh*128 + wwb];
            *(float4*)&sbuf[(ci*18 + r)*40 + c4*4] = v;
        }
        __syncthreads();
        #pragma unroll 2
        for (int ci = 0; ci < 8; ci++){
            float ws_[4][9];
            #pragma unroll
            for (int i=0;i<4;i++){
                const float* wp = wgt + ((size_t)(cog8 + ch4 + i)*CI + (cc0+ci))*9;
                #pragma unroll
                for (int k=0;k<9;k++) ws_[i][k] = wp[k];
            }
            #pragma unroll
            for (int r=0;r<3;r++){
                const float* rowp = &sbuf[(ci*18 + ty + r)*40 + wq*4 + 3];
                float rin[6];
                rin[0] = rowp[0];
                float4 mid = *(const float4*)(rowp+1);
                rin[1]=mid.x; rin[2]=mid.y; rin[3]=mid.z; rin[4]=mid.w;
                rin[5] = rowp[5];
                #pragma unroll
                for (int i=0;i<4;i++){
                    #pragma unroll
                    for (int dx=0;dx<3;dx++){
                        float wv = ws_[i][r*3+dx];
                        #pragma unroll
                        for (int j=0;j<4;j++)
                            acc[i][j] = fmaf(wv, rin[j+dx], acc[i][j]);
                    }
                }
            }
        }
        __syncthreads();
    }
    const int h = h0 + ty;
    const int wbase = w0 + wq*4;
    #pragma unroll
    for (int i=0;i<4;i++){
        float t0=acc[i][0], t1=acc[i][1], t2=acc[i][2], t3=acc[i][3];
        if (GELU_OUT){ t0=geluf(t0); t1=geluf(t1); t2=geluf(t2); t3=geluf(t3); }
        *(float4*)&out[(size_t)(cog8+ch4+i)*16384 + h*128 + wbase] =
            make_float4(t0,t1,t2,t3);
    }
}

// ---------------------------------------------------------------------------
// CO=1 conv (pred2). grid 64 blocks, block = 2 h-rows x 128 w.
__global__ __launch_bounds__(256) void conv3x3_co1_kernel(
    const float* __restrict__ in, const float* __restrict__ wgt,
    const float* __restrict__ bias, float* __restrict__ out, int CI)
{
    __shared__ float tile[16][4][128];
    const int h0 = blockIdx.x*2;
    const int hl = threadIdx.x >> 7;      // 0..1
    const int w  = threadIdx.x & 127;
    float acc = bias[0];
    for (int cc0 = 0; cc0 < CI; cc0 += 16){
        for (int e = threadIdx.x; e < 2048; e += 256){
            int c4 = e & 31, r = (e>>5)&3, ci = e>>7;
            int hh = h0 - 1 + r;
            float4 v = make_float4(0.f,0.f,0.f,0.f);
            if ((unsigned)hh < 128u)
                v = *(const float4*)&in[(size_t)(cc0+ci)*16384 + hh*128 + c4*4];
            *(float4*)&tile[ci][r][c4*4] = v;
        }
        __syncthreads();
        #pragma unroll 4
        for (int ci=0; ci<16; ci++){
            float w_s[9];
            #pragma unroll
            for (int k=0;k<9;k++) w_s[k] = wgt[(size_t)(cc0+ci)*9 + k];
            #pragma unroll
            for (int r=0;r<3;r++){
                #pragma unroll
                for (int dx=0;dx<3;dx++){
                    int col = w + dx - 1;
                    float x = ((unsigned)col < 128u) ? tile[ci][hl+r][col] : 0.f;
                    acc = fmaf(w_s[r*3+dx], x, acc);
                }
            }
        }
        __syncthreads();
    }
    out[(size_t)(h0+hl)*128 + w] = acc;
}

// ---------------------------------------------------------------------------
// C[M,N] = A[M,K] * W[N,K]^T.  BM=128 BN=64 BK=16, 256 thr, 8x4 per thread.
__global__ __launch_bounds__(256) void gemm_kernel(
    const float* __restrict__ A, const float* __restrict__ W,
    float* __restrict__ C, int M, int N, int K)
{
    __shared__ float As[16][132];
    __shared__ float Ws[16][68];
    const int tid = threadIdx.x;
    const int tx = tid & 15;
    const int ty = tid >> 4;
    const int m0 = blockIdx.x * 128;
    const int n0 = blockIdx.y * 64;

    float acc[8][4] = {};

    const int arow  = tid >> 2;   // 0..63
    const int acol4 = tid & 3;    // k chunk

    for (int k0 = 0; k0 < K; k0 += 16){
        #pragma unroll
        for (int half=0; half<2; half++){
            int r = arow + half*64;
            float4 v = *(const float4*)&A[(size_t)(m0+r)*K + k0 + acol4*4];
            As[acol4*4+0][r] = v.x;
            As[acol4*4+1][r] = v.y;
            As[acol4*4+2][r] = v.z;
            As[acol4*4+3][r] = v.w;
        }
        {
            int r = arow;
            float4 v = make_float4(0.f,0.f,0.f,0.f);
            if (n0 + r < N) v = *(const float4*)&W[(size_t)(n0+r)*K + k0 + acol4*4];
            Ws[acol4*4+0][r] = v.x;
            Ws[acol4*4+1][r] = v.y;
            Ws[acol4*4+2][r] = v.z;
            Ws[acol4*4+3][r] = v.w;
        }
        __syncthreads();
        #pragma unroll
        for (int k=0;k<16;k++){
            float4 a0 = *(const float4*)&As[k][ty*8];
            float4 a1 = *(const float4*)&As[k][ty*8+4];
            float4 bv = *(const float4*)&Ws[k][tx*4];
            float a[8] = {a0.x,a0.y,a0.z,a0.w,a1.x,a1.y,a1.z,a1.w};
            float b[4] = {bv.x,bv.y,bv.z,bv.w};
            #pragma unroll
            for (int i=0;i<8;i++)
                #pragma unroll
                for (int j=0;j<4;j++)
                    acc[i][j] = fmaf(a[i], b[j], acc[i][j]);
        }
        __syncthreads();
    }
    #pragma unroll
    for (int i=0;i<8;i++){
        int m = m0 + ty*8 + i;
        int n = n0 + tx*4;
        if (n < N)
            *(float4*)&C[(size_t)m*N + n] = make_float4(acc[i][0],acc[i][1],acc[i][2],acc[i][3]);
    }
}

// ---------------------------------------------------------------------------
// depthwise causal conv1d (k=4) + silu.  xz [NTOK,512] (xs = cols 0..255)
__global__ __launch_bounds__(256) void conv1d_silu_kernel(
    const float* __restrict__ xz, const float* __restrict__ cw,
    const float* __restrict__ cb, float* __restrict__ U)
{
    const int m = blockIdx.x;
    const int d = threadIdx.x;
    const int t = m & 127;
    float4 w4 = *(const float4*)&cw[d*4];
    float wj[4] = {w4.x, w4.y, w4.z, w4.w};
    float s = cb[d];
    #pragma unroll
    for (int j=0;j<4;j++){
        int tt = t - 3 + j;
        if (tt >= 0) s = fmaf(wj[j], xz[(size_t)(m - 3 + j)*512 + d], s);
    }
    U[(size_t)m*256 + d] = siluf(s);
}

// ---------------------------------------------------------------------------
// fused: delta(dt-proj+softplus) + selective scan + D-skip + silu(z) gate.
// grid 128 blocks (one per sequence), 256 threads (one per d).
// reads: U (u), xz cols[256,512) (z), proj (dt/B/C uniform rows, s_loads)
// writes: U in place with final gated output.
__global__ __launch_bounds__(256) void scan_fused_kernel(
    const float* __restrict__ xz, float* __restrict__ U,
    const float* __restrict__ proj, const float* __restrict__ dtw,
    const float* __restrict__ dtb, const float* __restrict__ Alog,
    const float* __restrict__ Dp)
{
    const int b = blockIdx.x;
    const int d = threadIdx.x;
    float A[16], h[16];
    #pragma unroll
    for (int s=0;s<16;s++){ A[s] = -__expf(Alog[d*16+s]); h[s]=0.f; }
    float4 dw0 = *(const float4*)&dtw[d*8];
    float4 dw1 = *(const float4*)&dtw[d*8+4];
    const float dtbv = dtb[d];
    const float Dv = Dp[d];

    int m = b*128;
    float uv = U[(size_t)m*256 + d];
    float zv = xz[(size_t)m*512 + 256 + d];
    for (int t=0; t<128; t++){
        float uv_n = 0.f, zv_n = 0.f;
        if (t < 127){
            uv_n = U[(size_t)(m+1)*256 + d];
            zv_n = xz[(size_t)(m+1)*512 + 256 + d];
        }
        const float* p = proj + (size_t)m*40;
        float dt = dtbv;
        dt = fmaf(p[0],dw0.x,fmaf(p[1],dw0.y,fmaf(p[2],dw0.z,fmaf(p[3],dw0.w,dt))));
        dt = fmaf(p[4],dw1.x,fmaf(p[5],dw1.y,fmaf(p[6],dw1.z,fmaf(p[7],dw1.w,dt))));
        float dv = softplusf(dt);
        float du = dv*uv;
        float y = 0.f;
        #pragma unroll
        for (int s=0;s<16;s++){
            float dA = __expf(dv*A[s]);
            h[s] = fmaf(dA, h[s], du*p[8+s]);
            y = fmaf(h[s], p[24+s], y);
        }
        U[(size_t)m*256 + d] = (y + uv*Dv) * siluf(zv);
        m++; uv = uv_n; zv = zv_n;
    }
}

// ---------------------------------------------------------------------------
// feats[c,h,w] -> out[w*ows + h*ohs + c]   (per-h 128x128 transpose)
__global__ __launch_bounds__(256) void transpose_cw_kernel(
    const float* __restrict__ feats, float* __restrict__ out,
    int ows, int ohs)
{
    __shared__ float tile[32][33];
    const int h = blockIdx.z;
    const int c0 = blockIdx.y*32, w0 = blockIdx.x*32;
    const int lx = threadIdx.x & 31, ly = threadIdx.x >> 5;
    #pragma unroll
    for (int i=0;i<4;i++){
        int c = c0 + ly + i*8;
        tile[ly+i*8][lx] = feats[(size_t)c*16384 + h*128 + w0 + lx];
    }
    __syncthreads();
    #pragma unroll
    for (int i=0;i<4;i++){
        int w = w0 + ly + i*8;
        out[(size_t)w*ows + (size_t)h*ohs + c0 + lx] = tile[lx][ly+i*8];
    }
}

// FH[c,h,w] = XH[w,h,c] + XW[h,w,c]
__global__ __launch_bounds__(256) void fuse_transpose_kernel(
    const float* __restrict__ XH, const float* __restrict__ XW,
    float* __restrict__ FH)
{
    __shared__ float tile[32][33];
    const int h = blockIdx.z;
    const int c0 = blockIdx.y*32, w0 = blockIdx.x*32;
    const int lx = threadIdx.x & 31, ly = threadIdx.x >> 5;
    #pragma unroll
    for (int i=0;i<4;i++){
        int w = w0 + ly + i*8;
        float v = XH[(size_t)w*16384 + h*128 + c0 + lx]
                + XW[(size_t)h*16384 + w*128 + c0 + lx];
        tile[ly+i*8][lx] = v;   // [w_local][c_local]
    }
    __syncthreads();
    #pragma unroll
    for (int i=0;i<4;i++){
        int c = c0 + ly + i*8;
        FH[(size_t)c*16384 + h*128 + w0 + lx] = tile[lx][ly+i*8];
    }
}

// ---------------------------------------------------------------------------
extern "C" void kernel_launch(void* const* d_in, const int* in_sizes, int n_in,
                              void* d_out, int out_size, void* d_ws, size_t ws_size,
                              hipStream_t stream)
{
    const float* x        = (const float*)d_in[0];
    const float* enc1_w   = (const float*)d_in[1];
    const float* enc1_b   = (const float*)d_in[2];
    const float* enc2_w   = (const float*)d_in[3];
    const float* enc2_b   = (const float*)d_in[4];
    const float* m_in_w   = (const float*)d_in[5];
    const float* m_conv_w = (const float*)d_in[6];
    const float* m_conv_b = (const float*)d_in[7];
    const float* m_xproj_w= (const float*)d_in[8];
    const float* m_dt_w   = (const float*)d_in[9];
    const float* m_dt_b   = (const float*)d_in[10];
    const float* m_Alog   = (const float*)d_in[11];
    const float* m_D      = (const float*)d_in[12];
    const float* m_out_w  = (const float*)d_in[13];
    const float* fus_w    = (const float*)d_in[14];
    const float* fus_b    = (const float*)d_in[15];
    const float* pred1_w  = (const float*)d_in[16];
    const float* pred1_b  = (const float*)d_in[17];
    const float* pred2_w  = (const float*)d_in[18];
    const float* pred2_b  = (const float*)d_in[19];
    float* out = (float*)d_out;

    float* ws    = (float*)d_ws;
    float* FEATS = ws;                         // 2M floats
    float* XH    = ws +  2u*1024*1024;         // 2M
    float* XW    = ws +  4u*1024*1024;         // 2M
    float* XZ    = ws +  6u*1024*1024;         // 8M  [NTOK,512]
    float* U     = ws + 14u*1024*1024;         // 4M  [NTOK,256]
    float* PROJ  = ws + 18u*1024*1024;         // 640K [NTOK,40]
    // liveness-based aliases within XZ (dead outside the mamba stacks):
    float* T0 = XZ;                  // conv1 output
    float* FH = XZ;                  // feats_h + feats_w
    float* G1 = XZ + 2u*1024*1024;   // fus conv output
    float* G2 = XZ + 4u*1024*1024;   // pred1 output

    const dim3 rgrid(4, 8, 16);   // new conv: 512 blocks

    // encoder
    conv3x3_kernel<true ><<<dim3(2,8,16), 256, 0, stream>>>(x, enc1_w, enc1_b, T0, 1, 128);
    conv3x3_rf_kernel<false><<<rgrid, 256, 0, stream>>>(T0, enc2_w, enc2_b, FEATS, 128);

    // layouts for the two scan directions
    transpose_cw_kernel<<<dim3(4,4,128), 256, 0, stream>>>(FEATS, XH, 16384, 128); // [w,h,c]
    transpose_cw_kernel<<<dim3(4,4,128), 256, 0, stream>>>(FEATS, XW, 128, 16384); // [h,w,c]

    for (int pass = 0; pass < 2; pass++){
        float* Xact = pass ? XW : XH;
        for (int l = 0; l < 3; l++){
            gemm_kernel<<<dim3(128,8), 256, 0, stream>>>(Xact, m_in_w + (size_t)l*512*128, XZ, NTOK, 512, 128);
            conv1d_silu_kernel<<<NTOK, 256, 0, stream>>>(XZ, m_conv_w + (size_t)l*256*4, m_conv_b + (size_t)l*256, U);
            gemm_kernel<<<dim3(128,1), 256, 0, stream>>>(U, m_xproj_w + (size_t)l*40*256, PROJ, NTOK, 40, 256);
            scan_fused_kernel<<<128, 256, 0, stream>>>(XZ, U, PROJ,
                m_dt_w + (size_t)l*256*8, m_dt_b + (size_t)l*256,
                m_Alog + (size_t)l*256*16, m_D + (size_t)l*256);
            gemm_kernel<<<dim3(128,2), 256, 0, stream>>>(U, m_out_w + (size_t)l*128*256, Xact, NTOK, 128, 256);
        }
    }

    fuse_transpose_kernel<<<dim3(4,4,128), 256, 0, stream>>>(XH, XW, FH);

    // decoder
    conv3x3_rf_kernel<false><<<rgrid, 256, 0, stream>>>(FH, fus_w,   fus_b,   G1, 128);
    conv3x3_rf_kernel<true ><<<rgrid, 256, 0, stream>>>(G1, pred1_w, pred1_b, G2, 128);
    conv3x3_co1_kernel<<<64, 256, 0, stream>>>(G2, pred2_w, pred2_b, out, 128);
}

// Round 5
// 1522.346 us; speedup vs baseline: 1.9662x; 1.2697x over previous
//
#include <hip/hip_runtime.h>
#include <math.h>

#define NTOK 16384   // 128 sequences * 128 steps

__device__ __forceinline__ float geluf(float x){
    return 0.5f*x*(1.0f+erff(x*0.70710678118654752f));
}
__device__ __forceinline__ float siluf(float x){
    return x/(1.0f+__expf(-x));
}
__device__ __forceinline__ float softplusf(float x){
    return (x>20.0f)? x : log1pf(__expf(x));
}

// ---------------------------------------------------------------------------
// ORIGINAL conv (kept only for enc1, CI=1 -> single ci iteration, cheap)
template<bool GELU_OUT>
__global__ __launch_bounds__(256) void conv3x3_kernel(
    const float* __restrict__ in, const float* __restrict__ wgt,
    const float* __restrict__ bias, float* __restrict__ out,
    int CI, int CO)
{
    __shared__ float tile[18][68];
    const int tx = threadIdx.x & 15;
    const int ty = threadIdx.x >> 4;
    const int w0 = blockIdx.x * 64;
    const int h0 = blockIdx.y * 16;
    const int cog = blockIdx.z * 8;

    float acc[8][4];
    #pragma unroll
    for (int i=0;i<8;i++){
        float b = (cog+i < CO) ? bias[cog+i] : 0.f;
        #pragma unroll
        for (int j=0;j<4;j++) acc[i][j] = b;
    }

    for (int ci=0; ci<CI; ci++){
        const float* inp = in + ci*16384;
        for (int e = threadIdx.x; e < 18*66; e += 256){
            int r = e/66, cc = e - r*66;
            int hh = h0 - 1 + r, ww = w0 - 1 + cc;
            float v = 0.f;
            if ((unsigned)hh < 128u && (unsigned)ww < 128u) v = inp[hh*128+ww];
            tile[r][cc] = v;
        }
        __syncthreads();
        float rin[3][8];
        #pragma unroll
        for (int r=0;r<3;r++){
            float4 a = *(const float4*)&tile[ty+r][tx*4];
            float4 b = *(const float4*)&tile[ty+r][tx*4+4];
            rin[r][0]=a.x; rin[r][1]=a.y; rin[r][2]=a.z; rin[r][3]=a.w;
            rin[r][4]=b.x; rin[r][5]=b.y; rin[r][6]=b.z; rin[r][7]=b.w;
        }
        #pragma unroll
        for (int co=0; co<8; co++){
            if (cog+co < CO) {
                const float* wp = wgt + ((cog+co)*CI + ci)*9;
                #pragma unroll
                for (int r=0;r<3;r++){
                    #pragma unroll
                    for (int dx=0;dx<3;dx++){
                        float wv = wp[r*3+dx];
                        #pragma unroll
                        for (int j=0;j<4;j++)
                            acc[co][j] = fmaf(wv, rin[r][j+dx], acc[co][j]);
                    }
                }
            }
        }
        __syncthreads();
    }
    const int h = h0 + ty;
    const int wbase = w0 + tx*4;
    #pragma unroll
    for (int co=0; co<8; co++){
        if (cog+co < CO){
            float t0 = acc[co][0], t1 = acc[co][1], t2 = acc[co][2], t3 = acc[co][3];
            if (GELU_OUT){ t0=geluf(t0); t1=geluf(t1); t2=geluf(t2); t3=geluf(t3); }
            *(float4*)&out[(cog+co)*16384 + h*128 + wbase] = make_float4(t0,t1,t2,t3);
        }
    }
}

// ---------------------------------------------------------------------------
// conv: CI multiple of 8, CO multiple of 8. grid (4,8,CO/8) = 512 blocks.
template<bool GELU_OUT>
__global__ __launch_bounds__(256) void conv3x3_rf_kernel(
    const float* __restrict__ in, const float* __restrict__ wgt,
    const float* __restrict__ bias, float* __restrict__ out,
    int CI)
{
    __shared__ float sbuf[8*18*40];
    const int wq = threadIdx.x & 7;
    const int ty = (threadIdx.x >> 3) & 15;
    const int ch4 = __builtin_amdgcn_readfirstlane((threadIdx.x >> 7) << 2); // 0 or 4
    const int w0 = blockIdx.x * 32;
    const int h0 = blockIdx.y * 16;
    const int cog8 = blockIdx.z * 8;

    float acc[4][4];
    #pragma unroll
    for (int i=0;i<4;i++){
        float b = bias[cog8 + ch4 + i];
        #pragma unroll
        for (int j=0;j<4;j++) acc[i][j] = b;
    }

    for (int cc0 = 0; cc0 < CI; cc0 += 8){
        for (int e = threadIdx.x; e < 1440; e += 256){
            int ci  = e / 180;
            int rem = e - ci*180;
            int r   = rem / 10;
            int c4  = rem - r*10;
            int hh  = h0 - 1 + r;
            int wwb = w0 - 4 + c4*4;
            float4 v = make_float4(0.f,0.f,0.f,0.f);
            if ((unsigned)hh < 128u && (unsigned)wwb < 128u)
                v = *(const float4*)&in[(size_t)(cc0+ci)*16384 + hh*128 + wwb];
            *(float4*)&sbuf[(ci*18 + r)*40 + c4*4] = v;
        }
        __syncthreads();
        #pragma unroll 2
        for (int ci = 0; ci < 8; ci++){
            float ws_[4][9];
            #pragma unroll
            for (int i=0;i<4;i++){
                const float* wp = wgt + ((size_t)(cog8 + ch4 + i)*CI + (cc0+ci))*9;
                #pragma unroll
                for (int k=0;k<9;k++) ws_[i][k] = wp[k];
            }
            #pragma unroll
            for (int r=0;r<3;r++){
                const float* rowp = &sbuf[(ci*18 + ty + r)*40 + wq*4 + 3];
                float rin[6];
                rin[0] = rowp[0];
                float4 mid = *(const float4*)(rowp+1);
                rin[1]=mid.x; rin[2]=mid.y; rin[3]=mid.z; rin[4]=mid.w;
                rin[5] = rowp[5];
                #pragma unroll
                for (int i=0;i<4;i++){
                    #pragma unroll
                    for (int dx=0;dx<3;dx++){
                        float wv = ws_[i][r*3+dx];
                        #pragma unroll
                        for (int j=0;j<4;j++)
                            acc[i][j] = fmaf(wv, rin[j+dx], acc[i][j]);
                    }
                }
            }
        }
        __syncthreads();
    }
    const int h = h0 + ty;
    const int wbase = w0 + wq*4;
    #pragma unroll
    for (int i=0;i<4;i++){
        float t0=acc[i][0], t1=acc[i][1], t2=acc[i][2], t3=acc[i][3];
        if (GELU_OUT){ t0=geluf(t0); t1=geluf(t1); t2=geluf(t2); t3=geluf(t3); }
        *(float4*)&out[(size_t)(cog8+ch4+i)*16384 + h*128 + wbase] =
            make_float4(t0,t1,t2,t3);
    }
}

// ---------------------------------------------------------------------------
// CO=1 conv (pred2). grid 64 blocks, block = 2 h-rows x 128 w.
__global__ __launch_bounds__(256) void conv3x3_co1_kernel(
    const float* __restrict__ in, const float* __restrict__ wgt,
    const float* __restrict__ bias, float* __restrict__ out, int CI)
{
    __shared__ float tile[16][4][128];
    const int h0 = blockIdx.x*2;
    const int hl = threadIdx.x >> 7;      // 0..1
    const int w  = threadIdx.x & 127;
    float acc = bias[0];
    for (int cc0 = 0; cc0 < CI; cc0 += 16){
        for (int e = threadIdx.x; e < 2048; e += 256){
            int c4 = e & 31, r = (e>>5)&3, ci = e>>7;
            int hh = h0 - 1 + r;
            float4 v = make_float4(0.f,0.f,0.f,0.f);
            if ((unsigned)hh < 128u)
                v = *(const float4*)&in[(size_t)(cc0+ci)*16384 + hh*128 + c4*4];
            *(float4*)&tile[ci][r][c4*4] = v;
        }
        __syncthreads();
        #pragma unroll 4
        for (int ci=0; ci<16; ci++){
            float w_s[9];
            #pragma unroll
            for (int k=0;k<9;k++) w_s[k] = wgt[(size_t)(cc0+ci)*9 + k];
            #pragma unroll
            for (int r=0;r<3;r++){
                #pragma unroll
                for (int dx=0;dx<3;dx++){
                    int col = w + dx - 1;
                    float x = ((unsigned)col < 128u) ? tile[ci][hl+r][col] : 0.f;
                    acc = fmaf(w_s[r*3+dx], x, acc);
                }
            }
        }
        __syncthreads();
    }
    out[(size_t)(h0+hl)*128 + w] = acc;
}

// ---------------------------------------------------------------------------
// C[M,N] = A[M,K] * W[N,K]^T.  BM=128 BN=64 BK=16, 256 thr, 8x4 per thread.
__global__ __launch_bounds__(256) void gemm_kernel(
    const float* __restrict__ A, const float* __restrict__ W,
    float* __restrict__ C, int M, int N, int K)
{
    __shared__ float As[16][132];
    __shared__ float Ws[16][68];
    const int tid = threadIdx.x;
    const int tx = tid & 15;
    const int ty = tid >> 4;
    const int m0 = blockIdx.x * 128;
    const int n0 = blockIdx.y * 64;

    float acc[8][4] = {};

    const int arow  = tid >> 2;   // 0..63
    const int acol4 = tid & 3;    // k chunk

    for (int k0 = 0; k0 < K; k0 += 16){
        #pragma unroll
        for (int half=0; half<2; half++){
            int r = arow + half*64;
            float4 v = *(const float4*)&A[(size_t)(m0+r)*K + k0 + acol4*4];
            As[acol4*4+0][r] = v.x;
            As[acol4*4+1][r] = v.y;
            As[acol4*4+2][r] = v.z;
            As[acol4*4+3][r] = v.w;
        }
        {
            int r = arow;
            float4 v = make_float4(0.f,0.f,0.f,0.f);
            if (n0 + r < N) v = *(const float4*)&W[(size_t)(n0+r)*K + k0 + acol4*4];
            Ws[acol4*4+0][r] = v.x;
            Ws[acol4*4+1][r] = v.y;
            Ws[acol4*4+2][r] = v.z;
            Ws[acol4*4+3][r] = v.w;
        }
        __syncthreads();
        #pragma unroll
        for (int k=0;k<16;k++){
            float4 a0 = *(const float4*)&As[k][ty*8];
            float4 a1 = *(const float4*)&As[k][ty*8+4];
            float4 bv = *(const float4*)&Ws[k][tx*4];
            float a[8] = {a0.x,a0.y,a0.z,a0.w,a1.x,a1.y,a1.z,a1.w};
            float b[4] = {bv.x,bv.y,bv.z,bv.w};
            #pragma unroll
            for (int i=0;i<8;i++)
                #pragma unroll
                for (int j=0;j<4;j++)
                    acc[i][j] = fmaf(a[i], b[j], acc[i][j]);
        }
        __syncthreads();
    }
    #pragma unroll
    for (int i=0;i<8;i++){
        int m = m0 + ty*8 + i;
        int n = n0 + tx*4;
        if (n < N)
            *(float4*)&C[(size_t)m*N + n] = make_float4(acc[i][0],acc[i][1],acc[i][2],acc[i][3]);
    }
}

// ---------------------------------------------------------------------------
// depthwise causal conv1d (k=4) + silu.  xz [NTOK,512] (xs = cols 0..255)
__global__ __launch_bounds__(256) void conv1d_silu_kernel(
    const float* __restrict__ xz, const float* __restrict__ cw,
    const float* __restrict__ cb, float* __restrict__ U)
{
    const int m = blockIdx.x;
    const int d = threadIdx.x;
    const int t = m & 127;
    float4 w4 = *(const float4*)&cw[d*4];
    float wj[4] = {w4.x, w4.y, w4.z, w4.w};
    float s = cb[d];
    #pragma unroll
    for (int j=0;j<4;j++){
        int tt = t - 3 + j;
        if (tt >= 0) s = fmaf(wj[j], xz[(size_t)(m - 3 + j)*512 + d], s);
    }
    U[(size_t)m*256 + d] = siluf(s);
}

// ---------------------------------------------------------------------------
// fused: delta(dt-proj+softplus) + selective scan + D-skip + silu(z) gate.
// grid (4 ch-groups, 128 seqs), 64 threads = 1 wave per block (512 blocks,
// 2 blocks/CU -> all CUs busy). Register prefetch pipeline: t+1's proj row
// (10 x float4), u, z loaded with clamped unconditional addresses so the
// compiler can hoist them above the exp/fma block of step t.
__global__ __launch_bounds__(64) void scan_fused_kernel(
    const float* __restrict__ xz, float* __restrict__ U,
    const float* __restrict__ proj, const float* __restrict__ dtw,
    const float* __restrict__ dtb, const float* __restrict__ Alog,
    const float* __restrict__ Dp)
{
    const int b = blockIdx.y;
    const int d = blockIdx.x*64 + threadIdx.x;
    float A[16], h[16];
    #pragma unroll
    for (int s=0;s<16;s++){ A[s] = -__expf(Alog[d*16+s]); h[s]=0.f; }
    float4 dw0 = *(const float4*)&dtw[d*8];
    float4 dw1 = *(const float4*)&dtw[d*8+4];
    const float dtbv = dtb[d];
    const float Dv = Dp[d];

    const int m0 = b*128;
    float uv = U[(size_t)m0*256 + d];
    float zv = xz[(size_t)m0*512 + 256 + d];
    float4 P[10];
    #pragma unroll
    for (int q=0;q<10;q++) P[q] = *(const float4*)&proj[(size_t)m0*40 + q*4];

    for (int t=0; t<128; t++){
        const int m  = m0 + t;
        const int mn = (t < 127) ? (m+1) : m;   // clamped: loads stay unconditional
        float uv_n = U[(size_t)mn*256 + d];
        float zv_n = xz[(size_t)mn*512 + 256 + d];
        float4 Pn[10];
        #pragma unroll
        for (int q=0;q<10;q++) Pn[q] = *(const float4*)&proj[(size_t)mn*40 + q*4];

        float dt = dtbv;
        dt = fmaf(P[0].x,dw0.x,fmaf(P[0].y,dw0.y,fmaf(P[0].z,dw0.z,fmaf(P[0].w,dw0.w,dt))));
        dt = fmaf(P[1].x,dw1.x,fmaf(P[1].y,dw1.y,fmaf(P[1].z,dw1.z,fmaf(P[1].w,dw1.w,dt))));
        float dv = softplusf(dt);
        float du = dv*uv;
        const float Bv[16] = {P[2].x,P[2].y,P[2].z,P[2].w, P[3].x,P[3].y,P[3].z,P[3].w,
                              P[4].x,P[4].y,P[4].z,P[4].w, P[5].x,P[5].y,P[5].z,P[5].w};
        const float Cv[16] = {P[6].x,P[6].y,P[6].z,P[6].w, P[7].x,P[7].y,P[7].z,P[7].w,
                              P[8].x,P[8].y,P[8].z,P[8].w, P[9].x,P[9].y,P[9].z,P[9].w};
        float y = 0.f;
        #pragma unroll
        for (int s=0;s<16;s++){
            float dA = __expf(dv*A[s]);
            h[s] = fmaf(dA, h[s], du*Bv[s]);
            y = fmaf(h[s], Cv[s], y);
        }
        U[(size_t)m*256 + d] = (y + uv*Dv) * siluf(zv);
        uv = uv_n; zv = zv_n;
        #pragma unroll
        for (int q=0;q<10;q++) P[q] = Pn[q];
    }
}

// ---------------------------------------------------------------------------
// feats[c,h,w] -> out[w*ows + h*ohs + c]   (per-h 128x128 transpose)
__global__ __launch_bounds__(256) void transpose_cw_kernel(
    const float* __restrict__ feats, float* __restrict__ out,
    int ows, int ohs)
{
    __shared__ float tile[32][33];
    const int h = blockIdx.z;
    const int c0 = blockIdx.y*32, w0 = blockIdx.x*32;
    const int lx = threadIdx.x & 31, ly = threadIdx.x >> 5;
    #pragma unroll
    for (int i=0;i<4;i++){
        int c = c0 + ly + i*8;
        tile[ly+i*8][lx] = feats[(size_t)c*16384 + h*128 + w0 + lx];
    }
    __syncthreads();
    #pragma unroll
    for (int i=0;i<4;i++){
        int w = w0 + ly + i*8;
        out[(size_t)w*ows + (size_t)h*ohs + c0 + lx] = tile[lx][ly+i*8];
    }
}

// FH[c,h,w] = XH[w,h,c] + XW[h,w,c]
__global__ __launch_bounds__(256) void fuse_transpose_kernel(
    const float* __restrict__ XH, const float* __restrict__ XW,
    float* __restrict__ FH)
{
    __shared__ float tile[32][33];
    const int h = blockIdx.z;
    const int c0 = blockIdx.y*32, w0 = blockIdx.x*32;
    const int lx = threadIdx.x & 31, ly = threadIdx.x >> 5;
    #pragma unroll
    for (int i=0;i<4;i++){
        int w = w0 + ly + i*8;
        float v = XH[(size_t)w*16384 + h*128 + c0 + lx]
                + XW[(size_t)h*16384 + w*128 + c0 + lx];
        tile[ly+i*8][lx] = v;   // [w_local][c_local]
    }
    __syncthreads();
    #pragma unroll
    for (int i=0;i<4;i++){
        int c = c0 + ly + i*8;
        FH[(size_t)c*16384 + h*128 + w0 + lx] = tile[lx][ly+i*8];
    }
}

// ---------------------------------------------------------------------------
extern "C" void kernel_launch(void* const* d_in, const int* in_sizes, int n_in,
                              void* d_out, int out_size, void* d_ws, size_t ws_size,
                              hipStream_t stream)
{
    const float* x        = (const float*)d_in[0];
    const float* enc1_w   = (const float*)d_in[1];
    const float* enc1_b   = (const float*)d_in[2];
    const float* enc2_w   = (const float*)d_in[3];
    const float* enc2_b   = (const float*)d_in[4];
    const float* m_in_w   = (const float*)d_in[5];
    const float* m_conv_w = (const float*)d_in[6];
    const float* m_conv_b = (const float*)d_in[7];
    const float* m_xproj_w= (const float*)d_in[8];
    const float* m_dt_w   = (const float*)d_in[9];
    const float* m_dt_b   = (const float*)d_in[10];
    const float* m_Alog   = (const float*)d_in[11];
    const float* m_D      = (const float*)d_in[12];
    const float* m_out_w  = (const float*)d_in[13];
    const float* fus_w    = (const float*)d_in[14];
    const float* fus_b    = (const float*)d_in[15];
    const float* pred1_w  = (const float*)d_in[16];
    const float* pred1_b  = (const float*)d_in[17];
    const float* pred2_w  = (const float*)d_in[18];
    const float* pred2_b  = (const float*)d_in[19];
    float* out = (float*)d_out;

    float* ws    = (float*)d_ws;
    float* FEATS = ws;                         // 2M floats
    float* XH    = ws +  2u*1024*1024;         // 2M
    float* XW    = ws +  4u*1024*1024;         // 2M
    float* XZ    = ws +  6u*1024*1024;         // 8M  [NTOK,512]
    float* U     = ws + 14u*1024*1024;         // 4M  [NTOK,256]
    float* PROJ  = ws + 18u*1024*1024;         // 640K [NTOK,40]
    // liveness-based aliases within XZ (dead outside the mamba stacks):
    float* T0 = XZ;                  // conv1 output
    float* FH = XZ;                  // feats_h + feats_w
    float* G1 = XZ + 2u*1024*1024;   // fus conv output
    float* G2 = XZ + 4u*1024*1024;   // pred1 output

    const dim3 rgrid(4, 8, 16);   // conv: 512 blocks

    // encoder
    conv3x3_kernel<true ><<<dim3(2,8,16), 256, 0, stream>>>(x, enc1_w, enc1_b, T0, 1, 128);
    conv3x3_rf_kernel<false><<<rgrid, 256, 0, stream>>>(T0, enc2_w, enc2_b, FEATS, 128);

    // layouts for the two scan directions
    transpose_cw_kernel<<<dim3(4,4,128), 256, 0, stream>>>(FEATS, XH, 16384, 128); // [w,h,c]
    transpose_cw_kernel<<<dim3(4,4,128), 256, 0, stream>>>(FEATS, XW, 128, 16384); // [h,w,c]

    for (int pass = 0; pass < 2; pass++){
        float* Xact = pass ? XW : XH;
        for (int l = 0; l < 3; l++){
            gemm_kernel<<<dim3(128,8), 256, 0, stream>>>(Xact, m_in_w + (size_t)l*512*128, XZ, NTOK, 512, 128);
            conv1d_silu_kernel<<<NTOK, 256, 0, stream>>>(XZ, m_conv_w + (size_t)l*256*4, m_conv_b + (size_t)l*256, U);
            gemm_kernel<<<dim3(128,1), 256, 0, stream>>>(U, m_xproj_w + (size_t)l*40*256, PROJ, NTOK, 40, 256);
            scan_fused_kernel<<<dim3(4,128), 64, 0, stream>>>(XZ, U, PROJ,
                m_dt_w + (size_t)l*256*8, m_dt_b + (size_t)l*256,
                m_Alog + (size_t)l*256*16, m_D + (size_t)l*256);
            gemm_kernel<<<dim3(128,2), 256, 0, stream>>>(U, m_out_w + (size_t)l*128*256, Xact, NTOK, 128, 256);
        }
    }

    fuse_transpose_kernel<<<dim3(4,4,128), 256, 0, stream>>>(XH, XW, FH);

    // decoder
    conv3x3_rf_kernel<false><<<rgrid, 256, 0, stream>>>(FH, fus_w,   fus_b,   G1, 128);
    conv3x3_rf_kernel<true ><<<rgrid, 256, 0, stream>>>(G1, pred1_w, pred1_b, G2, 128);
    conv3x3_co1_kernel<<<64, 256, 0, stream>>>(G2, pred2_w, pred2_b, out, 128);
}

// Round 6
// 1519.845 us; speedup vs baseline: 1.9694x; 1.0016x over previous
//
#include <hip/hip_runtime.h>
#include <math.h>

#define NTOK 16384   // 128 sequences * 128 steps

__device__ __forceinline__ float geluf(float x){
    return 0.5f*x*(1.0f+erff(x*0.70710678118654752f));
}
__device__ __forceinline__ float siluf(float x){
    return x/(1.0f+__expf(-x));
}
__device__ __forceinline__ float softplusf(float x){
    return (x>20.0f)? x : log1pf(__expf(x));
}

// ---------------------------------------------------------------------------
// ORIGINAL conv (kept only for enc1, CI=1 -> single ci iteration, cheap)
template<bool GELU_OUT>
__global__ __launch_bounds__(256) void conv3x3_kernel(
    const float* __restrict__ in, const float* __restrict__ wgt,
    const float* __restrict__ bias, float* __restrict__ out,
    int CI, int CO)
{
    __shared__ float tile[18][68];
    const int tx = threadIdx.x & 15;
    const int ty = threadIdx.x >> 4;
    const int w0 = blockIdx.x * 64;
    const int h0 = blockIdx.y * 16;
    const int cog = blockIdx.z * 8;

    float acc[8][4];
    #pragma unroll
    for (int i=0;i<8;i++){
        float b = (cog+i < CO) ? bias[cog+i] : 0.f;
        #pragma unroll
        for (int j=0;j<4;j++) acc[i][j] = b;
    }

    for (int ci=0; ci<CI; ci++){
        const float* inp = in + ci*16384;
        for (int e = threadIdx.x; e < 18*66; e += 256){
            int r = e/66, cc = e - r*66;
            int hh = h0 - 1 + r, ww = w0 - 1 + cc;
            float v = 0.f;
            if ((unsigned)hh < 128u && (unsigned)ww < 128u) v = inp[hh*128+ww];
            tile[r][cc] = v;
        }
        __syncthreads();
        float rin[3][8];
        #pragma unroll
        for (int r=0;r<3;r++){
            float4 a = *(const float4*)&tile[ty+r][tx*4];
            float4 b = *(const float4*)&tile[ty+r][tx*4+4];
            rin[r][0]=a.x; rin[r][1]=a.y; rin[r][2]=a.z; rin[r][3]=a.w;
            rin[r][4]=b.x; rin[r][5]=b.y; rin[r][6]=b.z; rin[r][7]=b.w;
        }
        #pragma unroll
        for (int co=0; co<8; co++){
            if (cog+co < CO) {
                const float* wp = wgt + ((cog+co)*CI + ci)*9;
                #pragma unroll
                for (int r=0;r<3;r++){
                    #pragma unroll
                    for (int dx=0;dx<3;dx++){
                        float wv = wp[r*3+dx];
                        #pragma unroll
                        for (int j=0;j<4;j++)
                            acc[co][j] = fmaf(wv, rin[r][j+dx], acc[co][j]);
                    }
                }
            }
        }
        __syncthreads();
    }
    const int h = h0 + ty;
    const int wbase = w0 + tx*4;
    #pragma unroll
    for (int co=0; co<8; co++){
        if (cog+co < CO){
            float t0 = acc[co][0], t1 = acc[co][1], t2 = acc[co][2], t3 = acc[co][3];
            if (GELU_OUT){ t0=geluf(t0); t1=geluf(t1); t2=geluf(t2); t3=geluf(t3); }
            *(float4*)&out[(cog+co)*16384 + h*128 + wbase] = make_float4(t0,t1,t2,t3);
        }
    }
}

// ---------------------------------------------------------------------------
// conv: CI multiple of 8, CO multiple of 8. grid (4,8,CO/8) = 512 blocks.
// All LDS reads are aligned ds_read_b128 (3 per (ci,r), window [3..8] of 12):
// scalar reads at +3/+8 had addr%4 fixed -> 8 banks only -> 8-way conflict
// (3e7 conflict cycles/dispatch in round 5). Aligned b128 at wq*4+{0,4,8}
// gives distinct 16B slots across each 8-lane phase -> conflict-free.
template<bool GELU_OUT>
__global__ __launch_bounds__(256) void conv3x3_rf_kernel(
    const float* __restrict__ in, const float* __restrict__ wgt,
    const float* __restrict__ bias, float* __restrict__ out,
    int CI)
{
    __shared__ float sbuf[8*18*40];
    const int wq = threadIdx.x & 7;
    const int ty = (threadIdx.x >> 3) & 15;
    const int ch4 = __builtin_amdgcn_readfirstlane((threadIdx.x >> 7) << 2); // 0 or 4
    const int w0 = blockIdx.x * 32;
    const int h0 = blockIdx.y * 16;
    const int cog8 = blockIdx.z * 8;

    float acc[4][4];
    #pragma unroll
    for (int i=0;i<4;i++){
        float b = bias[cog8 + ch4 + i];
        #pragma unroll
        for (int j=0;j<4;j++) acc[i][j] = b;
    }

    for (int cc0 = 0; cc0 < CI; cc0 += 8){
        for (int e = threadIdx.x; e < 1440; e += 256){
            int ci  = e / 180;
            int rem = e - ci*180;
            int r   = rem / 10;
            int c4  = rem - r*10;
            int hh  = h0 - 1 + r;
            int wwb = w0 - 4 + c4*4;
            float4 v = make_float4(0.f,0.f,0.f,0.f);
            if ((unsigned)hh < 128u && (unsigned)wwb < 128u)
                v = *(const float4*)&in[(size_t)(cc0+ci)*16384 + hh*128 + wwb];
            *(float4*)&sbuf[(ci*18 + r)*40 + c4*4] = v;
        }
        __syncthreads();
        #pragma unroll 2
        for (int ci = 0; ci < 8; ci++){
            float ws_[4][9];
            #pragma unroll
            for (int i=0;i<4;i++){
                const float* wp = wgt + ((size_t)(cog8 + ch4 + i)*CI + (cc0+ci))*9;
                #pragma unroll
                for (int k=0;k<9;k++) ws_[i][k] = wp[k];
            }
            #pragma unroll
            for (int r=0;r<3;r++){
                const float* rowp = &sbuf[(ci*18 + ty + r)*40 + wq*4];
                float4 q0 = *(const float4*)(rowp);
                float4 q1 = *(const float4*)(rowp+4);
                float4 q2 = *(const float4*)(rowp+8);
                float rin[12] = {q0.x,q0.y,q0.z,q0.w,
                                 q1.x,q1.y,q1.z,q1.w,
                                 q2.x,q2.y,q2.z,q2.w};
                #pragma unroll
                for (int i=0;i<4;i++){
                    #pragma unroll
                    for (int dx=0;dx<3;dx++){
                        float wv = ws_[i][r*3+dx];
                        #pragma unroll
                        for (int j=0;j<4;j++)
                            acc[i][j] = fmaf(wv, rin[3+j+dx], acc[i][j]);
                    }
                }
            }
        }
        __syncthreads();
    }
    const int h = h0 + ty;
    const int wbase = w0 + wq*4;
    #pragma unroll
    for (int i=0;i<4;i++){
        float t0=acc[i][0], t1=acc[i][1], t2=acc[i][2], t3=acc[i][3];
        if (GELU_OUT){ t0=geluf(t0); t1=geluf(t1); t2=geluf(t2); t3=geluf(t3); }
        *(float4*)&out[(size_t)(cog8+ch4+i)*16384 + h*128 + wbase] =
            make_float4(t0,t1,t2,t3);
    }
}

// ---------------------------------------------------------------------------
// CO=1 conv (pred2). grid 64 blocks, block = 2 h-rows x 128 w.
__global__ __launch_bounds__(256) void conv3x3_co1_kernel(
    const float* __restrict__ in, const float* __restrict__ wgt,
    const float* __restrict__ bias, float* __restrict__ out, int CI)
{
    __shared__ float tile[16][4][128];
    const int h0 = blockIdx.x*2;
    const int hl = threadIdx.x >> 7;      // 0..1
    const int w  = threadIdx.x & 127;
    float acc = bias[0];
    for (int cc0 = 0; cc0 < CI; cc0 += 16){
        for (int e = threadIdx.x; e < 2048; e += 256){
            int c4 = e & 31, r = (e>>5)&3, ci = e>>7;
            int hh = h0 - 1 + r;
            float4 v = make_float4(0.f,0.f,0.f,0.f);
            if ((unsigned)hh < 128u)
                v = *(const float4*)&in[(size_t)(cc0+ci)*16384 + hh*128 + c4*4];
            *(float4*)&tile[ci][r][c4*4] = v;
        }
        __syncthreads();
        #pragma unroll 4
        for (int ci=0; ci<16; ci++){
            float w_s[9];
            #pragma unroll
            for (int k=0;k<9;k++) w_s[k] = wgt[(size_t)(cc0+ci)*9 + k];
            #pragma unroll
            for (int r=0;r<3;r++){
                #pragma unroll
                for (int dx=0;dx<3;dx++){
                    int col = w + dx - 1;
                    float x = ((unsigned)col < 128u) ? tile[ci][hl+r][col] : 0.f;
                    acc = fmaf(w_s[r*3+dx], x, acc);
                }
            }
        }
        __syncthreads();
    }
    out[(size_t)(h0+hl)*128 + w] = acc;
}

// ---------------------------------------------------------------------------
// C[M,N] = A[M,K] * W[N,K]^T.  BM=128 BN=64 BK=16, 256 thr, 8x4 per thread.
__global__ __launch_bounds__(256) void gemm_kernel(
    const float* __restrict__ A, const float* __restrict__ W,
    float* __restrict__ C, int M, int N, int K)
{
    __shared__ float As[16][132];
    __shared__ float Ws[16][68];
    const int tid = threadIdx.x;
    const int tx = tid & 15;
    const int ty = tid >> 4;
    const int m0 = blockIdx.x * 128;
    const int n0 = blockIdx.y * 64;

    float acc[8][4] = {};

    const int arow  = tid >> 2;   // 0..63
    const int acol4 = tid & 3;    // k chunk

    for (int k0 = 0; k0 < K; k0 += 16){
        #pragma unroll
        for (int half=0; half<2; half++){
            int r = arow + half*64;
            float4 v = *(const float4*)&A[(size_t)(m0+r)*K + k0 + acol4*4];
            As[acol4*4+0][r] = v.x;
            As[acol4*4+1][r] = v.y;
            As[acol4*4+2][r] = v.z;
            As[acol4*4+3][r] = v.w;
        }
        {
            int r = arow;
            float4 v = make_float4(0.f,0.f,0.f,0.f);
            if (n0 + r < N) v = *(const float4*)&W[(size_t)(n0+r)*K + k0 + acol4*4];
            Ws[acol4*4+0][r] = v.x;
            Ws[acol4*4+1][r] = v.y;
            Ws[acol4*4+2][r] = v.z;
            Ws[acol4*4+3][r] = v.w;
        }
        __syncthreads();
        #pragma unroll
        for (int k=0;k<16;k++){
            float4 a0 = *(const float4*)&As[k][ty*8];
            float4 a1 = *(const float4*)&As[k][ty*8+4];
            float4 bv = *(const float4*)&Ws[k][tx*4];
            float a[8] = {a0.x,a0.y,a0.z,a0.w,a1.x,a1.y,a1.z,a1.w};
            float b[4] = {bv.x,bv.y,bv.z,bv.w};
            #pragma unroll
            for (int i=0;i<8;i++)
                #pragma unroll
                for (int j=0;j<4;j++)
                    acc[i][j] = fmaf(a[i], b[j], acc[i][j]);
        }
        __syncthreads();
    }
    #pragma unroll
    for (int i=0;i<8;i++){
        int m = m0 + ty*8 + i;
        int n = n0 + tx*4;
        if (n < N)
            *(float4*)&C[(size_t)m*N + n] = make_float4(acc[i][0],acc[i][1],acc[i][2],acc[i][3]);
    }
}

// ---------------------------------------------------------------------------
// depthwise causal conv1d (k=4) + silu.  xz [NTOK,512] (xs = cols 0..255)
__global__ __launch_bounds__(256) void conv1d_silu_kernel(
    const float* __restrict__ xz, const float* __restrict__ cw,
    const float* __restrict__ cb, float* __restrict__ U)
{
    const int m = blockIdx.x;
    const int d = threadIdx.x;
    const int t = m & 127;
    float4 w4 = *(const float4*)&cw[d*4];
    float wj[4] = {w4.x, w4.y, w4.z, w4.w};
    float s = cb[d];
    #pragma unroll
    for (int j=0;j<4;j++){
        int tt = t - 3 + j;
        if (tt >= 0) s = fmaf(wj[j], xz[(size_t)(m - 3 + j)*512 + d], s);
    }
    U[(size_t)m*256 + d] = siluf(s);
}

// ---------------------------------------------------------------------------
// fused: delta(dt-proj+softplus) + selective scan + D-skip + silu(z) gate.
// grid (4 ch-groups, 128 seqs), 64 threads = 1 wave per block (512 blocks,
// 2 blocks/CU -> all CUs busy). Register prefetch pipeline.
__global__ __launch_bounds__(64) void scan_fused_kernel(
    const float* __restrict__ xz, float* __restrict__ U,
    const float* __restrict__ proj, const float* __restrict__ dtw,
    const float* __restrict__ dtb, const float* __restrict__ Alog,
    const float* __restrict__ Dp)
{
    const int b = blockIdx.y;
    const int d = blockIdx.x*64 + threadIdx.x;
    float A[16], h[16];
    #pragma unroll
    for (int s=0;s<16;s++){ A[s] = -__expf(Alog[d*16+s]); h[s]=0.f; }
    float4 dw0 = *(const float4*)&dtw[d*8];
    float4 dw1 = *(const float4*)&dtw[d*8+4];
    const float dtbv = dtb[d];
    const float Dv = Dp[d];

    const int m0 = b*128;
    float uv = U[(size_t)m0*256 + d];
    float zv = xz[(size_t)m0*512 + 256 + d];
    float4 P[10];
    #pragma unroll
    for (int q=0;q<10;q++) P[q] = *(const float4*)&proj[(size_t)m0*40 + q*4];

    for (int t=0; t<128; t++){
        const int m  = m0 + t;
        const int mn = (t < 127) ? (m+1) : m;   // clamped: loads stay unconditional
        float uv_n = U[(size_t)mn*256 + d];
        float zv_n = xz[(size_t)mn*512 + 256 + d];
        float4 Pn[10];
        #pragma unroll
        for (int q=0;q<10;q++) Pn[q] = *(const float4*)&proj[(size_t)mn*40 + q*4];

        float dt = dtbv;
        dt = fmaf(P[0].x,dw0.x,fmaf(P[0].y,dw0.y,fmaf(P[0].z,dw0.z,fmaf(P[0].w,dw0.w,dt))));
        dt = fmaf(P[1].x,dw1.x,fmaf(P[1].y,dw1.y,fmaf(P[1].z,dw1.z,fmaf(P[1].w,dw1.w,dt))));
        float dv = softplusf(dt);
        float du = dv*uv;
        const float Bv[16] = {P[2].x,P[2].y,P[2].z,P[2].w, P[3].x,P[3].y,P[3].z,P[3].w,
                              P[4].x,P[4].y,P[4].z,P[4].w, P[5].x,P[5].y,P[5].z,P[5].w};
        const float Cv[16] = {P[6].x,P[6].y,P[6].z,P[6].w, P[7].x,P[7].y,P[7].z,P[7].w,
                              P[8].x,P[8].y,P[8].z,P[8].w, P[9].x,P[9].y,P[9].z,P[9].w};
        float y = 0.f;
        #pragma unroll
        for (int s=0;s<16;s++){
            float dA = __expf(dv*A[s]);
            h[s] = fmaf(dA, h[s], du*Bv[s]);
            y = fmaf(h[s], Cv[s], y);
        }
        U[(size_t)m*256 + d] = (y + uv*Dv) * siluf(zv);
        uv = uv_n; zv = zv_n;
        #pragma unroll
        for (int q=0;q<10;q++) P[q] = Pn[q];
    }
}

// ---------------------------------------------------------------------------
// feats[c,h,w] -> out[w*ows + h*ohs + c]   (per-h 128x128 transpose)
__global__ __launch_bounds__(256) void transpose_cw_kernel(
    const float* __restrict__ feats, float* __restrict__ out,
    int ows, int ohs)
{
    __shared__ float tile[32][33];
    const int h = blockIdx.z;
    const int c0 = blockIdx.y*32, w0 = blockIdx.x*32;
    const int lx = threadIdx.x & 31, ly = threadIdx.x >> 5;
    #pragma unroll
    for (int i=0;i<4;i++){
        int c = c0 + ly + i*8;
        tile[ly+i*8][lx] = feats[(size_t)c*16384 + h*128 + w0 + lx];
    }
    __syncthreads();
    #pragma unroll
    for (int i=0;i<4;i++){
        int w = w0 + ly + i*8;
        out[(size_t)w*ows + (size_t)h*ohs + c0 + lx] = tile[lx][ly+i*8];
    }
}

// FH[c,h,w] = XH[w,h,c] + XW[h,w,c]
__global__ __launch_bounds__(256) void fuse_transpose_kernel(
    const float* __restrict__ XH, const float* __restrict__ XW,
    float* __restrict__ FH)
{
    __shared__ float tile[32][33];
    const int h = blockIdx.z;
    const int c0 = blockIdx.y*32, w0 = blockIdx.x*32;
    const int lx = threadIdx.x & 31, ly = threadIdx.x >> 5;
    #pragma unroll
    for (int i=0;i<4;i++){
        int w = w0 + ly + i*8;
        float v = XH[(size_t)w*16384 + h*128 + c0 + lx]
                + XW[(size_t)h*16384 + w*128 + c0 + lx];
        tile[ly+i*8][lx] = v;   // [w_local][c_local]
    }
    __syncthreads();
    #pragma unroll
    for (int i=0;i<4;i++){
        int c = c0 + ly + i*8;
        FH[(size_t)c*16384 + h*128 + w0 + lx] = tile[lx][ly+i*8];
    }
}

// ---------------------------------------------------------------------------
extern "C" void kernel_launch(void* const* d_in, const int* in_sizes, int n_in,
                              void* d_out, int out_size, void* d_ws, size_t ws_size,
                              hipStream_t stream)
{
    const float* x        = (const float*)d_in[0];
    const float* enc1_w   = (const float*)d_in[1];
    const float* enc1_b   = (const float*)d_in[2];
    const float* enc2_w   = (const float*)d_in[3];
    const float* enc2_b   = (const float*)d_in[4];
    const float* m_in_w   = (const float*)d_in[5];
    const float* m_conv_w = (const float*)d_in[6];
    const float* m_conv_b = (const float*)d_in[7];
    const float* m_xproj_w= (const float*)d_in[8];
    const float* m_dt_w   = (const float*)d_in[9];
    const float* m_dt_b   = (const float*)d_in[10];
    const float* m_Alog   = (const float*)d_in[11];
    const float* m_D      = (const float*)d_in[12];
    const float* m_out_w  = (const float*)d_in[13];
    const float* fus_w    = (const float*)d_in[14];
    const float* fus_b    = (const float*)d_in[15];
    const float* pred1_w  = (const float*)d_in[16];
    const float* pred1_b  = (const float*)d_in[17];
    const float* pred2_w  = (const float*)d_in[18];
    const float* pred2_b  = (const float*)d_in[19];
    float* out = (float*)d_out;

    float* ws    = (float*)d_ws;
    float* FEATS = ws;                         // 2M floats
    float* XH    = ws +  2u*1024*1024;         // 2M
    float* XW    = ws +  4u*1024*1024;         // 2M
    float* XZ    = ws +  6u*1024*1024;         // 8M  [NTOK,512]
    float* U     = ws + 14u*1024*1024;         // 4M  [NTOK,256]
    float* PROJ  = ws + 18u*1024*1024;         // 640K [NTOK,40]
    // liveness-based aliases within XZ (dead outside the mamba stacks):
    float* T0 = XZ;                  // conv1 output
    float* FH = XZ;                  // feats_h + feats_w
    float* G1 = XZ + 2u*1024*1024;   // fus conv output
    float* G2 = XZ + 4u*1024*1024;   // pred1 output

    const dim3 rgrid(4, 8, 16);   // conv: 512 blocks

    // encoder
    conv3x3_kernel<true ><<<dim3(2,8,16), 256, 0, stream>>>(x, enc1_w, enc1_b, T0, 1, 128);
    conv3x3_rf_kernel<false><<<rgrid, 256, 0, stream>>>(T0, enc2_w, enc2_b, FEATS, 128);

    // layouts for the two scan directions
    transpose_cw_kernel<<<dim3(4,4,128), 256, 0, stream>>>(FEATS, XH, 16384, 128); // [w,h,c]
    transpose_cw_kernel<<<dim3(4,4,128), 256, 0, stream>>>(FEATS, XW, 128, 16384); // [h,w,c]

    for (int pass = 0; pass < 2; pass++){
        float* Xact = pass ? XW : XH;
        for (int l = 0; l < 3; l++){
            gemm_kernel<<<dim3(128,8), 256, 0, stream>>>(Xact, m_in_w + (size_t)l*512*128, XZ, NTOK, 512, 128);
            conv1d_silu_kernel<<<NTOK, 256, 0, stream>>>(XZ, m_conv_w + (size_t)l*256*4, m_conv_b + (size_t)l*256, U);
            gemm_kernel<<<dim3(128,1), 256, 0, stream>>>(U, m_xproj_w + (size_t)l*40*256, PROJ, NTOK, 40, 256);
            scan_fused_kernel<<<dim3(4,128), 64, 0, stream>>>(XZ, U, PROJ,
                m_dt_w + (size_t)l*256*8, m_dt_b + (size_t)l*256,
                m_Alog + (size_t)l*256*16, m_D + (size_t)l*256);
            gemm_kernel<<<dim3(128,2), 256, 0, stream>>>(U, m_out_w + (size_t)l*128*256, Xact, NTOK, 128, 256);
        }
    }

    fuse_transpose_kernel<<<dim3(4,4,128), 256, 0, stream>>>(XH, XW, FH);

    // decoder
    conv3x3_rf_kernel<false><<<rgrid, 256, 0, stream>>>(FH, fus_w,   fus_b,   G1, 128);
    conv3x3_rf_kernel<true ><<<rgrid, 256, 0, stream>>>(G1, pred1_w, pred1_b, G2, 128);
    conv3x3_co1_kernel<<<64, 256, 0, stream>>>(G2, pred2_w, pred2_b, out, 128);
}

// Round 7
// 1452.483 us; speedup vs baseline: 2.0608x; 1.0464x over previous
//
#include <hip/hip_runtime.h>
#include <math.h>

#define NTOK 16384   // 128 sequences * 128 steps

typedef __attribute__((ext_vector_type(8))) short bf16x8;
typedef __attribute__((ext_vector_type(4))) float f32x4;

__device__ __forceinline__ float geluf(float x){
    return 0.5f*x*(1.0f+erff(x*0.70710678118654752f));
}
__device__ __forceinline__ float siluf(float x){
    return x/(1.0f+__expf(-x));
}
__device__ __forceinline__ float softplusf(float x){
    return (x>20.0f)? x : log1pf(__expf(x));
}
__device__ __forceinline__ void split_bf16(float x, unsigned short& h, unsigned short& l){
    union { float f; unsigned u; } c; c.f = x;
    h = (unsigned short)(c.u >> 16);
    union { unsigned u; float f; } hf; hf.u = c.u & 0xffff0000u;
    union { float f; unsigned u; } rc; rc.f = x - hf.f;
    l = (unsigned short)(rc.u >> 16);
}

// ---------------------------------------------------------------------------
// enc1 conv (CI=1), original structure - cheap, leave alone.
template<bool GELU_OUT>
__global__ __launch_bounds__(256) void conv3x3_kernel(
    const float* __restrict__ in, const float* __restrict__ wgt,
    const float* __restrict__ bias, float* __restrict__ out,
    int CI, int CO)
{
    __shared__ float tile[18][68];
    const int tx = threadIdx.x & 15;
    const int ty = threadIdx.x >> 4;
    const int w0 = blockIdx.x * 64;
    const int h0 = blockIdx.y * 16;
    const int cog = blockIdx.z * 8;

    float acc[8][4];
    #pragma unroll
    for (int i=0;i<8;i++){
        float b = (cog+i < CO) ? bias[cog+i] : 0.f;
        #pragma unroll
        for (int j=0;j<4;j++) acc[i][j] = b;
    }

    for (int ci=0; ci<CI; ci++){
        const float* inp = in + ci*16384;
        for (int e = threadIdx.x; e < 18*66; e += 256){
            int r = e/66, cc = e - r*66;
            int hh = h0 - 1 + r, ww = w0 - 1 + cc;
            float v = 0.f;
            if ((unsigned)hh < 128u && (unsigned)ww < 128u) v = inp[hh*128+ww];
            tile[r][cc] = v;
        }
        __syncthreads();
        float rin[3][8];
        #pragma unroll
        for (int r=0;r<3;r++){
            float4 a = *(const float4*)&tile[ty+r][tx*4];
            float4 b = *(const float4*)&tile[ty+r][tx*4+4];
            rin[r][0]=a.x; rin[r][1]=a.y; rin[r][2]=a.z; rin[r][3]=a.w;
            rin[r][4]=b.x; rin[r][5]=b.y; rin[r][6]=b.z; rin[r][7]=b.w;
        }
        #pragma unroll
        for (int co=0; co<8; co++){
            if (cog+co < CO) {
                const float* wp = wgt + ((cog+co)*CI + ci)*9;
                #pragma unroll
                for (int r=0;r<3;r++){
                    #pragma unroll
                    for (int dx=0;dx<3;dx++){
                        float wv = wp[r*3+dx];
                        #pragma unroll
                        for (int j=0;j<4;j++)
                            acc[co][j] = fmaf(wv, rin[r][j+dx], acc[co][j]);
                    }
                }
            }
        }
        __syncthreads();
    }
    const int h = h0 + ty;
    const int wbase = w0 + tx*4;
    #pragma unroll
    for (int co=0; co<8; co++){
        if (cog+co < CO){
            float t0 = acc[co][0], t1 = acc[co][1], t2 = acc[co][2], t3 = acc[co][3];
            if (GELU_OUT){ t0=geluf(t0); t1=geluf(t1); t2=geluf(t2); t3=geluf(t3); }
            *(float4*)&out[(cog+co)*16384 + h*128 + wbase] = make_float4(t0,t1,t2,t3);
        }
    }
}

// ---------------------------------------------------------------------------
// conv 128ci: grid (4,16,16) = 1024 blocks = 4 blocks/CU (16 waves/CU).
// tile 32w x 8h x 8co; thread (wq,ty,ch) = 4w x 2co. 12.8KB LDS.
template<bool GELU_OUT>
__global__ __launch_bounds__(256) void conv3x3_rf_kernel(
    const float* __restrict__ in, const float* __restrict__ wgt,
    const float* __restrict__ bias, float* __restrict__ out,
    int CI)
{
    __shared__ float sbuf[8*10*40];
    const int wq = threadIdx.x & 7;
    const int ty = (threadIdx.x >> 3) & 7;
    const int ch = __builtin_amdgcn_readfirstlane(threadIdx.x >> 6); // 0..3, wave-uniform
    const int w0 = blockIdx.x * 32;
    const int h0 = blockIdx.y * 8;
    const int cog8 = blockIdx.z * 8;

    float acc[2][4];
    #pragma unroll
    for (int i=0;i<2;i++){
        float b = bias[cog8 + ch*2 + i];
        #pragma unroll
        for (int j=0;j<4;j++) acc[i][j] = b;
    }

    for (int cc0 = 0; cc0 < CI; cc0 += 8){
        // stage 8 channels: rows h0-1..h0+8 (10), cols w0-4..w0+35 (10 float4)
        for (int e = threadIdx.x; e < 800; e += 256){
            int ci  = e / 100;
            int rem = e - ci*100;
            int r   = rem / 10;
            int c4  = rem - r*10;
            int hh  = h0 - 1 + r;
            int wwb = w0 - 4 + c4*4;
            float4 v = make_float4(0.f,0.f,0.f,0.f);
            if ((unsigned)hh < 128u && (unsigned)wwb < 128u)
                v = *(const float4*)&in[(size_t)(cc0+ci)*16384 + hh*128 + wwb];
            *(float4*)&sbuf[(ci*10 + r)*40 + c4*4] = v;
        }
        __syncthreads();
        #pragma unroll 2
        for (int ci = 0; ci < 8; ci++){
            float ws_[2][9];
            #pragma unroll
            for (int i=0;i<2;i++){
                const float* wp = wgt + ((size_t)(cog8 + ch*2 + i)*CI + (cc0+ci))*9;
                #pragma unroll
                for (int k=0;k<9;k++) ws_[i][k] = wp[k];
            }
            #pragma unroll
            for (int r=0;r<3;r++){
                const float* rowp = &sbuf[(ci*10 + ty + r)*40 + wq*4];
                float4 q0 = *(const float4*)(rowp);
                float4 q1 = *(const float4*)(rowp+4);
                float4 q2 = *(const float4*)(rowp+8);
                float rin[12] = {q0.x,q0.y,q0.z,q0.w,
                                 q1.x,q1.y,q1.z,q1.w,
                                 q2.x,q2.y,q2.z,q2.w};
                #pragma unroll
                for (int i=0;i<2;i++){
                    #pragma unroll
                    for (int dx=0;dx<3;dx++){
                        float wv = ws_[i][r*3+dx];
                        #pragma unroll
                        for (int j=0;j<4;j++)
                            acc[i][j] = fmaf(wv, rin[3+j+dx], acc[i][j]);
                    }
                }
            }
        }
        __syncthreads();
    }
    const int h = h0 + ty;
    const int wbase = w0 + wq*4;
    #pragma unroll
    for (int i=0;i<2;i++){
        float t0=acc[i][0], t1=acc[i][1], t2=acc[i][2], t3=acc[i][3];
        if (GELU_OUT){ t0=geluf(t0); t1=geluf(t1); t2=geluf(t2); t3=geluf(t3); }
        *(float4*)&out[(size_t)(cog8+ch*2+i)*16384 + h*128 + wbase] =
            make_float4(t0,t1,t2,t3);
    }
}

// ---------------------------------------------------------------------------
// CO=1 conv (pred2). grid 64 blocks, block = 2 h-rows x 128 w.
__global__ __launch_bounds__(256) void conv3x3_co1_kernel(
    const float* __restrict__ in, const float* __restrict__ wgt,
    const float* __restrict__ bias, float* __restrict__ out, int CI)
{
    __shared__ float tile[16][4][128];
    const int h0 = blockIdx.x*2;
    const int hl = threadIdx.x >> 7;      // 0..1
    const int w  = threadIdx.x & 127;
    float acc = bias[0];
    for (int cc0 = 0; cc0 < CI; cc0 += 16){
        for (int e = threadIdx.x; e < 2048; e += 256){
            int c4 = e & 31, r = (e>>5)&3, ci = e>>7;
            int hh = h0 - 1 + r;
            float4 v = make_float4(0.f,0.f,0.f,0.f);
            if ((unsigned)hh < 128u)
                v = *(const float4*)&in[(size_t)(cc0+ci)*16384 + hh*128 + c4*4];
            *(float4*)&tile[ci][r][c4*4] = v;
        }
        __syncthreads();
        #pragma unroll 4
        for (int ci=0; ci<16; ci++){
            float w_s[9];
            #pragma unroll
            for (int k=0;k<9;k++) w_s[k] = wgt[(size_t)(cc0+ci)*9 + k];
            #pragma unroll
            for (int r=0;r<3;r++){
                #pragma unroll
                for (int dx=0;dx<3;dx++){
                    int col = w + dx - 1;
                    float x = ((unsigned)col < 128u) ? tile[ci][hl+r][col] : 0.f;
                    acc = fmaf(w_s[r*3+dx], x, acc);
                }
            }
        }
        __syncthreads();
    }
    out[(size_t)(h0+hl)*128 + w] = acc;
}

// ---------------------------------------------------------------------------
// Split-bf16 MFMA GEMM: C[M,N] = A[M,K] * W[N,K]^T in ~fp32 precision.
// A = Ah + Al (truncation split); D = Ah*Bh + Ah*Bl + Al*Bh (Al*Bl dropped,
// ~2^-16 rel). BM=BN=64, BK=32, 256 thr = 4 waves, each wave 2x2 16x16 tiles.
// M % 64 == 0, K % 32 == 0, N arbitrary (masked).
__global__ __launch_bounds__(256) void gemm_mfma_kernel(
    const float* __restrict__ A, const float* __restrict__ W,
    float* __restrict__ C, int M, int N, int K)
{
    // row stride 48 ushorts (96B, 16B-aligned for b128 frag reads)
    __shared__ unsigned short Ah[64*48], Al[64*48], Bh[64*48], Bl[64*48];
    const int tid  = threadIdx.x;
    const int wave = tid >> 6;
    const int lane = tid & 63;
    const int wr   = wave >> 1;      // m-half of block tile
    const int wc   = wave & 1;       // n-half
    const int lrow = lane & 15;
    const int kg   = lane >> 4;      // k-group 0..3

    const int m0 = blockIdx.x * 64;
    const int n0 = blockIdx.y * 64;

    f32x4 acc[2][2];
    #pragma unroll
    for (int mi=0;mi<2;mi++)
        #pragma unroll
        for (int ni=0;ni<2;ni++)
            acc[mi][ni] = (f32x4){0.f,0.f,0.f,0.f};

    for (int k0 = 0; k0 < K; k0 += 32){
        // stage A: 64 rows x 32 k = 512 float4, 2 per thread
        #pragma unroll
        for (int it=0; it<2; it++){
            int idx = tid + it*256;
            int r = idx >> 3, c4 = idx & 7;
            float4 v = *(const float4*)&A[(size_t)(m0+r)*K + k0 + c4*4];
            unsigned short h[4], l[4];
            split_bf16(v.x, h[0], l[0]);
            split_bf16(v.y, h[1], l[1]);
            split_bf16(v.z, h[2], l[2]);
            split_bf16(v.w, h[3], l[3]);
            *(uint2*)&Ah[r*48 + c4*4] = make_uint2(h[0]|((unsigned)h[1]<<16), h[2]|((unsigned)h[3]<<16));
            *(uint2*)&Al[r*48 + c4*4] = make_uint2(l[0]|((unsigned)l[1]<<16), l[2]|((unsigned)l[3]<<16));
        }
        // stage B (W rows), zero-padded past N
        #pragma unroll
        for (int it=0; it<2; it++){
            int idx = tid + it*256;
            int r = idx >> 3, c4 = idx & 7;
            float4 v = make_float4(0.f,0.f,0.f,0.f);
            if (n0 + r < N) v = *(const float4*)&W[(size_t)(n0+r)*K + k0 + c4*4];
            unsigned short h[4], l[4];
            split_bf16(v.x, h[0], l[0]);
            split_bf16(v.y, h[1], l[1]);
            split_bf16(v.z, h[2], l[2]);
            split_bf16(v.w, h[3], l[3]);
            *(uint2*)&Bh[r*48 + c4*4] = make_uint2(h[0]|((unsigned)h[1]<<16), h[2]|((unsigned)h[3]<<16));
            *(uint2*)&Bl[r*48 + c4*4] = make_uint2(l[0]|((unsigned)l[1]<<16), l[2]|((unsigned)l[3]<<16));
        }
        __syncthreads();

        bf16x8 fah[2], fal[2], fbh[2], fbl[2];
        #pragma unroll
        for (int mi=0;mi<2;mi++){
            int row = (wr*2+mi)*16 + lrow;
            fah[mi] = *(const bf16x8*)&Ah[row*48 + kg*8];
            fal[mi] = *(const bf16x8*)&Al[row*48 + kg*8];
        }
        #pragma unroll
        for (int ni=0;ni<2;ni++){
            int row = (wc*2+ni)*16 + lrow;
            fbh[ni] = *(const bf16x8*)&Bh[row*48 + kg*8];
            fbl[ni] = *(const bf16x8*)&Bl[row*48 + kg*8];
        }
        #pragma unroll
        for (int mi=0;mi<2;mi++){
            #pragma unroll
            for (int ni=0;ni<2;ni++){
                acc[mi][ni] = __builtin_amdgcn_mfma_f32_16x16x32_bf16(fah[mi], fbh[ni], acc[mi][ni], 0,0,0);
                acc[mi][ni] = __builtin_amdgcn_mfma_f32_16x16x32_bf16(fah[mi], fbl[ni], acc[mi][ni], 0,0,0);
                acc[mi][ni] = __builtin_amdgcn_mfma_f32_16x16x32_bf16(fal[mi], fbh[ni], acc[mi][ni], 0,0,0);
            }
        }
        __syncthreads();
    }
    // C layout (m89-verified): col = lane&15, row = (lane>>4)*4 + reg
    #pragma unroll
    for (int mi=0;mi<2;mi++){
        #pragma unroll
        for (int ni=0;ni<2;ni++){
            int n = n0 + (wc*2+ni)*16 + lrow;
            if (n < N){
                #pragma unroll
                for (int r=0;r<4;r++){
                    int m = m0 + (wr*2+mi)*16 + kg*4 + r;
                    C[(size_t)m*N + n] = acc[mi][ni][r];
                }
            }
        }
    }
}

// ---------------------------------------------------------------------------
// depthwise causal conv1d (k=4) + silu.  xz [NTOK,512] (xs = cols 0..255)
__global__ __launch_bounds__(256) void conv1d_silu_kernel(
    const float* __restrict__ xz, const float* __restrict__ cw,
    const float* __restrict__ cb, float* __restrict__ U)
{
    const int m = blockIdx.x;
    const int d = threadIdx.x;
    const int t = m & 127;
    float4 w4 = *(const float4*)&cw[d*4];
    float wj[4] = {w4.x, w4.y, w4.z, w4.w};
    float s = cb[d];
    #pragma unroll
    for (int j=0;j<4;j++){
        int tt = t - 3 + j;
        if (tt >= 0) s = fmaf(wj[j], xz[(size_t)(m - 3 + j)*512 + d], s);
    }
    U[(size_t)m*256 + d] = siluf(s);
}

// ---------------------------------------------------------------------------
// fused: delta(dt-proj+softplus) + selective scan + D-skip + silu(z) gate.
// grid (4 ch-groups, 128 seqs), 64 thr/block; register prefetch pipeline.
__global__ __launch_bounds__(64) void scan_fused_kernel(
    const float* __restrict__ xz, float* __restrict__ U,
    const float* __restrict__ proj, const float* __restrict__ dtw,
    const float* __restrict__ dtb, const float* __restrict__ Alog,
    const float* __restrict__ Dp)
{
    const int b = blockIdx.y;
    const int d = blockIdx.x*64 + threadIdx.x;
    float A[16], h[16];
    #pragma unroll
    for (int s=0;s<16;s++){ A[s] = -__expf(Alog[d*16+s]); h[s]=0.f; }
    float4 dw0 = *(const float4*)&dtw[d*8];
    float4 dw1 = *(const float4*)&dtw[d*8+4];
    const float dtbv = dtb[d];
    const float Dv = Dp[d];

    const int m0 = b*128;
    float uv = U[(size_t)m0*256 + d];
    float zv = xz[(size_t)m0*512 + 256 + d];
    float4 P[10];
    #pragma unroll
    for (int q=0;q<10;q++) P[q] = *(const float4*)&proj[(size_t)m0*40 + q*4];

    for (int t=0; t<128; t++){
        const int m  = m0 + t;
        const int mn = (t < 127) ? (m+1) : m;   // clamped: loads stay unconditional
        float uv_n = U[(size_t)mn*256 + d];
        float zv_n = xz[(size_t)mn*512 + 256 + d];
        float4 Pn[10];
        #pragma unroll
        for (int q=0;q<10;q++) Pn[q] = *(const float4*)&proj[(size_t)mn*40 + q*4];

        float dt = dtbv;
        dt = fmaf(P[0].x,dw0.x,fmaf(P[0].y,dw0.y,fmaf(P[0].z,dw0.z,fmaf(P[0].w,dw0.w,dt))));
        dt = fmaf(P[1].x,dw1.x,fmaf(P[1].y,dw1.y,fmaf(P[1].z,dw1.z,fmaf(P[1].w,dw1.w,dt))));
        float dv = softplusf(dt);
        float du = dv*uv;
        const float Bv[16] = {P[2].x,P[2].y,P[2].z,P[2].w, P[3].x,P[3].y,P[3].z,P[3].w,
                              P[4].x,P[4].y,P[4].z,P[4].w, P[5].x,P[5].y,P[5].z,P[5].w};
        const float Cv[16] = {P[6].x,P[6].y,P[6].z,P[6].w, P[7].x,P[7].y,P[7].z,P[7].w,
                              P[8].x,P[8].y,P[8].z,P[8].w, P[9].x,P[9].y,P[9].z,P[9].w};
        float y = 0.f;
        #pragma unroll
        for (int s=0;s<16;s++){
            float dA = __expf(dv*A[s]);
            h[s] = fmaf(dA, h[s], du*Bv[s]);
            y = fmaf(h[s], Cv[s], y);
        }
        U[(size_t)m*256 + d] = (y + uv*Dv) * siluf(zv);
        uv = uv_n; zv = zv_n;
        #pragma unroll
        for (int q=0;q<10;q++) P[q] = Pn[q];
    }
}

// ---------------------------------------------------------------------------
// feats[c,h,w] -> out[w*ows + h*ohs + c]   (per-h 128x128 transpose)
__global__ __launch_bounds__(256) void transpose_cw_kernel(
    const float* __restrict__ feats, float* __restrict__ out,
    int ows, int ohs)
{
    __shared__ float tile[32][33];
    const int h = blockIdx.z;
    const int c0 = blockIdx.y*32, w0 = blockIdx.x*32;
    const int lx = threadIdx.x & 31, ly = threadIdx.x >> 5;
    #pragma unroll
    for (int i=0;i<4;i++){
        int c = c0 + ly + i*8;
        tile[ly+i*8][lx] = feats[(size_t)c*16384 + h*128 + w0 + lx];
    }
    __syncthreads();
    #pragma unroll
    for (int i=0;i<4;i++){
        int w = w0 + ly + i*8;
        out[(size_t)w*ows + (size_t)h*ohs + c0 + lx] = tile[lx][ly+i*8];
    }
}

// FH[c,h,w] = XH[w,h,c] + XW[h,w,c]
__global__ __launch_bounds__(256) void fuse_transpose_kernel(
    const float* __restrict__ XH, const float* __restrict__ XW,
    float* __restrict__ FH)
{
    __shared__ float tile[32][33];
    const int h = blockIdx.z;
    const int c0 = blockIdx.y*32, w0 = blockIdx.x*32;
    const int lx = threadIdx.x & 31, ly = threadIdx.x >> 5;
    #pragma unroll
    for (int i=0;i<4;i++){
        int w = w0 + ly + i*8;
        float v = XH[(size_t)w*16384 + h*128 + c0 + lx]
                + XW[(size_t)h*16384 + w*128 + c0 + lx];
        tile[ly+i*8][lx] = v;   // [w_local][c_local]
    }
    __syncthreads();
    #pragma unroll
    for (int i=0;i<4;i++){
        int c = c0 + ly + i*8;
        FH[(size_t)c*16384 + h*128 + w0 + lx] = tile[lx][ly+i*8];
    }
}

// ---------------------------------------------------------------------------
extern "C" void kernel_launch(void* const* d_in, const int* in_sizes, int n_in,
                              void* d_out, int out_size, void* d_ws, size_t ws_size,
                              hipStream_t stream)
{
    const float* x        = (const float*)d_in[0];
    const float* enc1_w   = (const float*)d_in[1];
    const float* enc1_b   = (const float*)d_in[2];
    const float* enc2_w   = (const float*)d_in[3];
    const float* enc2_b   = (const float*)d_in[4];
    const float* m_in_w   = (const float*)d_in[5];
    const float* m_conv_w = (const float*)d_in[6];
    const float* m_conv_b = (const float*)d_in[7];
    const float* m_xproj_w= (const float*)d_in[8];
    const float* m_dt_w   = (const float*)d_in[9];
    const float* m_dt_b   = (const float*)d_in[10];
    const float* m_Alog   = (const float*)d_in[11];
    const float* m_D      = (const float*)d_in[12];
    const float* m_out_w  = (const float*)d_in[13];
    const float* fus_w    = (const float*)d_in[14];
    const float* fus_b    = (const float*)d_in[15];
    const float* pred1_w  = (const float*)d_in[16];
    const float* pred1_b  = (const float*)d_in[17];
    const float* pred2_w  = (const float*)d_in[18];
    const float* pred2_b  = (const float*)d_in[19];
    float* out = (float*)d_out;

    float* ws    = (float*)d_ws;
    float* FEATS = ws;                         // 2M floats
    float* XH    = ws +  2u*1024*1024;         // 2M
    float* XW    = ws +  4u*1024*1024;         // 2M
    float* XZ    = ws +  6u*1024*1024;         // 8M  [NTOK,512]
    float* U     = ws + 14u*1024*1024;         // 4M  [NTOK,256]
    float* PROJ  = ws + 18u*1024*1024;         // 640K [NTOK,40]
    // liveness-based aliases within XZ (dead outside the mamba stacks):
    float* T0 = XZ;                  // conv1 output
    float* FH = XZ;                  // feats_h + feats_w
    float* G1 = XZ + 2u*1024*1024;   // fus conv output
    float* G2 = XZ + 4u*1024*1024;   // pred1 output

    const dim3 rgrid(4, 16, 16);   // conv: 1024 blocks, 4/CU

    // encoder
    conv3x3_kernel<true ><<<dim3(2,8,16), 256, 0, stream>>>(x, enc1_w, enc1_b, T0, 1, 128);
    conv3x3_rf_kernel<false><<<rgrid, 256, 0, stream>>>(T0, enc2_w, enc2_b, FEATS, 128);

    // layouts for the two scan directions
    transpose_cw_kernel<<<dim3(4,4,128), 256, 0, stream>>>(FEATS, XH, 16384, 128); // [w,h,c]
    transpose_cw_kernel<<<dim3(4,4,128), 256, 0, stream>>>(FEATS, XW, 128, 16384); // [h,w,c]

    for (int pass = 0; pass < 2; pass++){
        float* Xact = pass ? XW : XH;
        for (int l = 0; l < 3; l++){
            gemm_mfma_kernel<<<dim3(256,8), 256, 0, stream>>>(Xact, m_in_w + (size_t)l*512*128, XZ, NTOK, 512, 128);
            conv1d_silu_kernel<<<NTOK, 256, 0, stream>>>(XZ, m_conv_w + (size_t)l*256*4, m_conv_b + (size_t)l*256, U);
            gemm_mfma_kernel<<<dim3(256,1), 256, 0, stream>>>(U, m_xproj_w + (size_t)l*40*256, PROJ, NTOK, 40, 256);
            scan_fused_kernel<<<dim3(4,128), 64, 0, stream>>>(XZ, U, PROJ,
                m_dt_w + (size_t)l*256*8, m_dt_b + (size_t)l*256,
                m_Alog + (size_t)l*256*16, m_D + (size_t)l*256);
            gemm_mfma_kernel<<<dim3(256,2), 256, 0, stream>>>(U, m_out_w + (size_t)l*128*256, Xact, NTOK, 128, 256);
        }
    }

    fuse_transpose_kernel<<<dim3(4,4,128), 256, 0, stream>>>(XH, XW, FH);

    // decoder
    conv3x3_rf_kernel<false><<<rgrid, 256, 0, stream>>>(FH, fus_w,   fus_b,   G1, 128);
    conv3x3_rf_kernel<true ><<<rgrid, 256, 0, stream>>>(G1, pred1_w, pred1_b, G2, 128);
    conv3x3_co1_kernel<<<64, 256, 0, stream>>>(G2, pred2_w, pred2_b, out, 128);
}

// Round 8
// 1135.637 us; speedup vs baseline: 2.6357x; 1.2790x over previous
//
#include <hip/hip_runtime.h>
#include <math.h>

#define NTOK 16384   // 128 sequences * 128 steps

typedef __attribute__((ext_vector_type(8))) short bf16x8;
typedef __attribute__((ext_vector_type(4))) float f32x4;

__device__ __forceinline__ float geluf(float x){
    return 0.5f*x*(1.0f+erff(x*0.70710678118654752f));
}
__device__ __forceinline__ float siluf(float x){
    return x/(1.0f+__expf(-x));
}
__device__ __forceinline__ float softplusf(float x){
    return (x>20.0f)? x : log1pf(__expf(x));
}
__device__ __forceinline__ void split_bf16(float x, unsigned short& h, unsigned short& l){
    union { float f; unsigned u; } c; c.f = x;
    h = (unsigned short)(c.u >> 16);
    union { unsigned u; float f; } hf; hf.u = c.u & 0xffff0000u;
    union { float f; unsigned u; } rc; rc.f = x - hf.f;
    l = (unsigned short)(rc.u >> 16);
}

// ---------------------------------------------------------------------------
// enc1 conv (CI=1), original structure - cheap, leave alone.
template<bool GELU_OUT>
__global__ __launch_bounds__(256) void conv3x3_kernel(
    const float* __restrict__ in, const float* __restrict__ wgt,
    const float* __restrict__ bias, float* __restrict__ out,
    int CI, int CO)
{
    __shared__ float tile[18][68];
    const int tx = threadIdx.x & 15;
    const int ty = threadIdx.x >> 4;
    const int w0 = blockIdx.x * 64;
    const int h0 = blockIdx.y * 16;
    const int cog = blockIdx.z * 8;

    float acc[8][4];
    #pragma unroll
    for (int i=0;i<8;i++){
        float b = (cog+i < CO) ? bias[cog+i] : 0.f;
        #pragma unroll
        for (int j=0;j<4;j++) acc[i][j] = b;
    }

    for (int ci=0; ci<CI; ci++){
        const float* inp = in + ci*16384;
        for (int e = threadIdx.x; e < 18*66; e += 256){
            int r = e/66, cc = e - r*66;
            int hh = h0 - 1 + r, ww = w0 - 1 + cc;
            float v = 0.f;
            if ((unsigned)hh < 128u && (unsigned)ww < 128u) v = inp[hh*128+ww];
            tile[r][cc] = v;
        }
        __syncthreads();
        float rin[3][8];
        #pragma unroll
        for (int r=0;r<3;r++){
            float4 a = *(const float4*)&tile[ty+r][tx*4];
            float4 b = *(const float4*)&tile[ty+r][tx*4+4];
            rin[r][0]=a.x; rin[r][1]=a.y; rin[r][2]=a.z; rin[r][3]=a.w;
            rin[r][4]=b.x; rin[r][5]=b.y; rin[r][6]=b.z; rin[r][7]=b.w;
        }
        #pragma unroll
        for (int co=0; co<8; co++){
            if (cog+co < CO) {
                const float* wp = wgt + ((cog+co)*CI + ci)*9;
                #pragma unroll
                for (int r=0;r<3;r++){
                    #pragma unroll
                    for (int dx=0;dx<3;dx++){
                        float wv = wp[r*3+dx];
                        #pragma unroll
                        for (int j=0;j<4;j++)
                            acc[co][j] = fmaf(wv, rin[r][j+dx], acc[co][j]);
                    }
                }
            }
        }
        __syncthreads();
    }
    const int h = h0 + ty;
    const int wbase = w0 + tx*4;
    #pragma unroll
    for (int co=0; co<8; co++){
        if (cog+co < CO){
            float t0 = acc[co][0], t1 = acc[co][1], t2 = acc[co][2], t3 = acc[co][3];
            if (GELU_OUT){ t0=geluf(t0); t1=geluf(t1); t2=geluf(t2); t3=geluf(t3); }
            *(float4*)&out[(cog+co)*16384 + h*128 + wbase] = make_float4(t0,t1,t2,t3);
        }
    }
}

// ---------------------------------------------------------------------------
// weight split prepass: wgt [128co][128ci][3][3] f32 -> hi/lo bf16 in
// fragment-major layout [t][cog8][chunk4][kg4][lr16][j8] so the conv kernel's
// A-fragment loads are fully-coalesced contiguous 16B/lane (1KB/wave).
__global__ __launch_bounds__(256) void wsplit_kernel(
    const float* __restrict__ wgt, unsigned short* __restrict__ whi,
    unsigned short* __restrict__ wlo)
{
    int e = blockIdx.x*256 + threadIdx.x;   // < 147456
    int ci = e & 127, co = (e >> 7) & 127, t = e >> 14;
    float v = wgt[((co<<7)|ci)*9 + t];
    unsigned short h, l; split_bf16(v, h, l);
    int cog = co >> 4, lr = co & 15;
    int chk = ci >> 5, kg = (ci >> 3) & 3, j = ci & 7;
    int o = ((((t*8 + cog)*4 + chk)*4 + kg)*16 + lr)*8 + j;
    whi[o] = h; wlo[o] = l;
}

// ---------------------------------------------------------------------------
// conv2d 3x3 as 9-tap split-bf16 MFMA GEMM. CI=CO=128 fixed.
// block: 64 co (M) x 64 pixels (N = 4 h-rows x 16 w); grid (8,32,2) = 512.
// 4 waves: wave(wr,wc) owns 2 co-groups x 2 pixel-groups.
// K-loop: ci chunks of 32. Input staged pixel-major [6h][20w][40ci] bf16
// hi/lo in LDS (ci padded 32->40: b128 frag reads hit 8 distinct bank-groups).
// Weights read direct from global (pre-split, fragment-major, L2-resident).
template<bool GELU_OUT>
__global__ __launch_bounds__(256) void conv_mfma_kernel(
    const float* __restrict__ in, const unsigned short* __restrict__ whi,
    const unsigned short* __restrict__ wlo, const float* __restrict__ bias,
    float* __restrict__ out)
{
    __shared__ unsigned short sHi[6*20*40], sLo[6*20*40];
    const int tid  = threadIdx.x;
    const int wave = tid >> 6;
    const int lane = tid & 63;
    const int wr   = wave >> 1;
    const int wc   = wave & 1;
    const int lr   = lane & 15;
    const int kg   = lane >> 4;
    const int w0   = blockIdx.x * 16;
    const int h0   = blockIdx.y * 4;
    const int cogz = blockIdx.z * 4;     // co-group base (of 16) for this block

    f32x4 acc[2][2];
    #pragma unroll
    for (int cg=0;cg<2;cg++)
        #pragma unroll
        for (int pg=0;pg<2;pg++)
            acc[cg][pg] = (f32x4){0.f,0.f,0.f,0.f};

    for (int ch = 0; ch < 4; ch++){          // ci chunk of 32
        const int cc0 = ch*32;
        for (int e = tid; e < 3456; e += 256){
            int cil = e / 108;
            int rem = e - cil*108;
            int hl  = rem / 18;
            int wl  = rem - hl*18;
            int hh = h0 - 1 + hl, ww = w0 - 1 + wl;
            float v = 0.f;
            if ((unsigned)hh < 128u && (unsigned)ww < 128u)
                v = in[(size_t)(cc0+cil)*16384 + hh*128 + ww];
            unsigned short hi, lo; split_bf16(v, hi, lo);
            int o = (hl*20 + wl)*40 + cil;
            sHi[o] = hi; sLo[o] = lo;
        }
        __syncthreads();
        #pragma unroll
        for (int dy=0; dy<3; dy++){
            #pragma unroll
            for (int dx=0; dx<3; dx++){
                const int t = dy*3+dx;
                bf16x8 ah[2], al[2], bh[2], bl[2];
                #pragma unroll
                for (int cg=0; cg<2; cg++){
                    int cog = cogz + wr*2 + cg;
                    size_t off = ((size_t)(((t*8 + cog)*4 + ch)*4 + kg)*16 + lr)*8;
                    ah[cg] = *(const bf16x8*)&whi[off];
                    al[cg] = *(const bf16x8*)&wlo[off];
                }
                #pragma unroll
                for (int pg=0; pg<2; pg++){
                    int g = wc*2 + pg;
                    int o = ((g+dy)*20 + lr + dx)*40 + kg*8;
                    bh[pg] = *(const bf16x8*)&sHi[o];
                    bl[pg] = *(const bf16x8*)&sLo[o];
                }
                #pragma unroll
                for (int cg=0; cg<2; cg++){
                    #pragma unroll
                    for (int pg=0; pg<2; pg++){
                        acc[cg][pg] = __builtin_amdgcn_mfma_f32_16x16x32_bf16(ah[cg], bh[pg], acc[cg][pg], 0,0,0);
                        acc[cg][pg] = __builtin_amdgcn_mfma_f32_16x16x32_bf16(ah[cg], bl[pg], acc[cg][pg], 0,0,0);
                        acc[cg][pg] = __builtin_amdgcn_mfma_f32_16x16x32_bf16(al[cg], bh[pg], acc[cg][pg], 0,0,0);
                    }
                }
            }
        }
        __syncthreads();
    }
    // C layout (verified): col = lane&15 (pixel w), row = kg*4 + reg (co)
    #pragma unroll
    for (int cg=0; cg<2; cg++){
        #pragma unroll
        for (int pg=0; pg<2; pg++){
            int h = h0 + wc*2 + pg;
            int w = w0 + lr;
            #pragma unroll
            for (int r=0; r<4; r++){
                int co = (cogz + wr*2 + cg)*16 + kg*4 + r;
                float v = acc[cg][pg][r] + bias[co];
                if (GELU_OUT) v = geluf(v);
                out[(size_t)co*16384 + h*128 + w] = v;
            }
        }
    }
}

// ---------------------------------------------------------------------------
// CO=1 conv (pred2). grid 64 blocks, block = 2 h-rows x 128 w.
__global__ __launch_bounds__(256) void conv3x3_co1_kernel(
    const float* __restrict__ in, const float* __restrict__ wgt,
    const float* __restrict__ bias, float* __restrict__ out, int CI)
{
    __shared__ float tile[16][4][128];
    const int h0 = blockIdx.x*2;
    const int hl = threadIdx.x >> 7;      // 0..1
    const int w  = threadIdx.x & 127;
    float acc = bias[0];
    for (int cc0 = 0; cc0 < CI; cc0 += 16){
        for (int e = threadIdx.x; e < 2048; e += 256){
            int c4 = e & 31, r = (e>>5)&3, ci = e>>7;
            int hh = h0 - 1 + r;
            float4 v = make_float4(0.f,0.f,0.f,0.f);
            if ((unsigned)hh < 128u)
                v = *(const float4*)&in[(size_t)(cc0+ci)*16384 + hh*128 + c4*4];
            *(float4*)&tile[ci][r][c4*4] = v;
        }
        __syncthreads();
        #pragma unroll 4
        for (int ci=0; ci<16; ci++){
            float w_s[9];
            #pragma unroll
            for (int k=0;k<9;k++) w_s[k] = wgt[(size_t)(cc0+ci)*9 + k];
            #pragma unroll
            for (int r=0;r<3;r++){
                #pragma unroll
                for (int dx=0;dx<3;dx++){
                    int col = w + dx - 1;
                    float x = ((unsigned)col < 128u) ? tile[ci][hl+r][col] : 0.f;
                    acc = fmaf(w_s[r*3+dx], x, acc);
                }
            }
        }
        __syncthreads();
    }
    out[(size_t)(h0+hl)*128 + w] = acc;
}

// ---------------------------------------------------------------------------
// Split-bf16 MFMA GEMM: C[M,N] = A[M,K] * W[N,K]^T in ~fp32 precision.
// BM=BN=64, BK=32, 256 thr = 4 waves, each wave 2x2 16x16 tiles.
__global__ __launch_bounds__(256) void gemm_mfma_kernel(
    const float* __restrict__ A, const float* __restrict__ W,
    float* __restrict__ C, int M, int N, int K)
{
    __shared__ unsigned short Ah[64*48], Al[64*48], Bh[64*48], Bl[64*48];
    const int tid  = threadIdx.x;
    const int wave = tid >> 6;
    const int lane = tid & 63;
    const int wr   = wave >> 1;
    const int wc   = wave & 1;
    const int lrow = lane & 15;
    const int kg   = lane >> 4;

    const int m0 = blockIdx.x * 64;
    const int n0 = blockIdx.y * 64;

    f32x4 acc[2][2];
    #pragma unroll
    for (int mi=0;mi<2;mi++)
        #pragma unroll
        for (int ni=0;ni<2;ni++)
            acc[mi][ni] = (f32x4){0.f,0.f,0.f,0.f};

    for (int k0 = 0; k0 < K; k0 += 32){
        #pragma unroll
        for (int it=0; it<2; it++){
            int idx = tid + it*256;
            int r = idx >> 3, c4 = idx & 7;
            float4 v = *(const float4*)&A[(size_t)(m0+r)*K + k0 + c4*4];
            unsigned short h[4], l[4];
            split_bf16(v.x, h[0], l[0]);
            split_bf16(v.y, h[1], l[1]);
            split_bf16(v.z, h[2], l[2]);
            split_bf16(v.w, h[3], l[3]);
            *(uint2*)&Ah[r*48 + c4*4] = make_uint2(h[0]|((unsigned)h[1]<<16), h[2]|((unsigned)h[3]<<16));
            *(uint2*)&Al[r*48 + c4*4] = make_uint2(l[0]|((unsigned)l[1]<<16), l[2]|((unsigned)l[3]<<16));
        }
        #pragma unroll
        for (int it=0; it<2; it++){
            int idx = tid + it*256;
            int r = idx >> 3, c4 = idx & 7;
            float4 v = make_float4(0.f,0.f,0.f,0.f);
            if (n0 + r < N) v = *(const float4*)&W[(size_t)(n0+r)*K + k0 + c4*4];
            unsigned short h[4], l[4];
            split_bf16(v.x, h[0], l[0]);
            split_bf16(v.y, h[1], l[1]);
            split_bf16(v.z, h[2], l[2]);
            split_bf16(v.w, h[3], l[3]);
            *(uint2*)&Bh[r*48 + c4*4] = make_uint2(h[0]|((unsigned)h[1]<<16), h[2]|((unsigned)h[3]<<16));
            *(uint2*)&Bl[r*48 + c4*4] = make_uint2(l[0]|((unsigned)l[1]<<16), l[2]|((unsigned)l[3]<<16));
        }
        __syncthreads();

        bf16x8 fah[2], fal[2], fbh[2], fbl[2];
        #pragma unroll
        for (int mi=0;mi<2;mi++){
            int row = (wr*2+mi)*16 + lrow;
            fah[mi] = *(const bf16x8*)&Ah[row*48 + kg*8];
            fal[mi] = *(const bf16x8*)&Al[row*48 + kg*8];
        }
        #pragma unroll
        for (int ni=0;ni<2;ni++){
            int row = (wc*2+ni)*16 + lrow;
            fbh[ni] = *(const bf16x8*)&Bh[row*48 + kg*8];
            fbl[ni] = *(const bf16x8*)&Bl[row*48 + kg*8];
        }
        #pragma unroll
        for (int mi=0;mi<2;mi++){
            #pragma unroll
            for (int ni=0;ni<2;ni++){
                acc[mi][ni] = __builtin_amdgcn_mfma_f32_16x16x32_bf16(fah[mi], fbh[ni], acc[mi][ni], 0,0,0);
                acc[mi][ni] = __builtin_amdgcn_mfma_f32_16x16x32_bf16(fah[mi], fbl[ni], acc[mi][ni], 0,0,0);
                acc[mi][ni] = __builtin_amdgcn_mfma_f32_16x16x32_bf16(fal[mi], fbh[ni], acc[mi][ni], 0,0,0);
            }
        }
        __syncthreads();
    }
    #pragma unroll
    for (int mi=0;mi<2;mi++){
        #pragma unroll
        for (int ni=0;ni<2;ni++){
            int n = n0 + (wc*2+ni)*16 + lrow;
            if (n < N){
                #pragma unroll
                for (int r=0;r<4;r++){
                    int m = m0 + (wr*2+mi)*16 + kg*4 + r;
                    C[(size_t)m*N + n] = acc[mi][ni][r];
                }
            }
        }
    }
}

// ---------------------------------------------------------------------------
// depthwise causal conv1d (k=4) + silu.  xz [NTOK,512] (xs = cols 0..255)
__global__ __launch_bounds__(256) void conv1d_silu_kernel(
    const float* __restrict__ xz, const float* __restrict__ cw,
    const float* __restrict__ cb, float* __restrict__ U)
{
    const int m = blockIdx.x;
    const int d = threadIdx.x;
    const int t = m & 127;
    float4 w4 = *(const float4*)&cw[d*4];
    float wj[4] = {w4.x, w4.y, w4.z, w4.w};
    float s = cb[d];
    #pragma unroll
    for (int j=0;j<4;j++){
        int tt = t - 3 + j;
        if (tt >= 0) s = fmaf(wj[j], xz[(size_t)(m - 3 + j)*512 + d], s);
    }
    U[(size_t)m*256 + d] = siluf(s);
}

// ---------------------------------------------------------------------------
// fused: delta(dt-proj+softplus) + selective scan + D-skip + silu(z) gate.
__global__ __launch_bounds__(64) void scan_fused_kernel(
    const float* __restrict__ xz, float* __restrict__ U,
    const float* __restrict__ proj, const float* __restrict__ dtw,
    const float* __restrict__ dtb, const float* __restrict__ Alog,
    const float* __restrict__ Dp)
{
    const int b = blockIdx.y;
    const int d = blockIdx.x*64 + threadIdx.x;
    float A[16], h[16];
    #pragma unroll
    for (int s=0;s<16;s++){ A[s] = -__expf(Alog[d*16+s]); h[s]=0.f; }
    float4 dw0 = *(const float4*)&dtw[d*8];
    float4 dw1 = *(const float4*)&dtw[d*8+4];
    const float dtbv = dtb[d];
    const float Dv = Dp[d];

    const int m0 = b*128;
    float uv = U[(size_t)m0*256 + d];
    float zv = xz[(size_t)m0*512 + 256 + d];
    float4 P[10];
    #pragma unroll
    for (int q=0;q<10;q++) P[q] = *(const float4*)&proj[(size_t)m0*40 + q*4];

    for (int t=0; t<128; t++){
        const int m  = m0 + t;
        const int mn = (t < 127) ? (m+1) : m;
        float uv_n = U[(size_t)mn*256 + d];
        float zv_n = xz[(size_t)mn*512 + 256 + d];
        float4 Pn[10];
        #pragma unroll
        for (int q=0;q<10;q++) Pn[q] = *(const float4*)&proj[(size_t)mn*40 + q*4];

        float dt = dtbv;
        dt = fmaf(P[0].x,dw0.x,fmaf(P[0].y,dw0.y,fmaf(P[0].z,dw0.z,fmaf(P[0].w,dw0.w,dt))));
        dt = fmaf(P[1].x,dw1.x,fmaf(P[1].y,dw1.y,fmaf(P[1].z,dw1.z,fmaf(P[1].w,dw1.w,dt))));
        float dv = softplusf(dt);
        float du = dv*uv;
        const float Bv[16] = {P[2].x,P[2].y,P[2].z,P[2].w, P[3].x,P[3].y,P[3].z,P[3].w,
                              P[4].x,P[4].y,P[4].z,P[4].w, P[5].x,P[5].y,P[5].z,P[5].w};
        const float Cv[16] = {P[6].x,P[6].y,P[6].z,P[6].w, P[7].x,P[7].y,P[7].z,P[7].w,
                              P[8].x,P[8].y,P[8].z,P[8].w, P[9].x,P[9].y,P[9].z,P[9].w};
        float y = 0.f;
        #pragma unroll
        for (int s=0;s<16;s++){
            float dA = __expf(dv*A[s]);
            h[s] = fmaf(dA, h[s], du*Bv[s]);
            y = fmaf(h[s], Cv[s], y);
        }
        U[(size_t)m*256 + d] = (y + uv*Dv) * siluf(zv);
        uv = uv_n; zv = zv_n;
        #pragma unroll
        for (int q=0;q<10;q++) P[q] = Pn[q];
    }
}

// ---------------------------------------------------------------------------
// feats[c,h,w] -> out[w*ows + h*ohs + c]   (per-h 128x128 transpose)
__global__ __launch_bounds__(256) void transpose_cw_kernel(
    const float* __restrict__ feats, float* __restrict__ out,
    int ows, int ohs)
{
    __shared__ float tile[32][33];
    const int h = blockIdx.z;
    const int c0 = blockIdx.y*32, w0 = blockIdx.x*32;
    const int lx = threadIdx.x & 31, ly = threadIdx.x >> 5;
    #pragma unroll
    for (int i=0;i<4;i++){
        int c = c0 + ly + i*8;
        tile[ly+i*8][lx] = feats[(size_t)c*16384 + h*128 + w0 + lx];
    }
    __syncthreads();
    #pragma unroll
    for (int i=0;i<4;i++){
        int w = w0 + ly + i*8;
        out[(size_t)w*ows + (size_t)h*ohs + c0 + lx] = tile[lx][ly+i*8];
    }
}

// FH[c,h,w] = XH[w,h,c] + XW[h,w,c]
__global__ __launch_bounds__(256) void fuse_transpose_kernel(
    const float* __restrict__ XH, const float* __restrict__ XW,
    float* __restrict__ FH)
{
    __shared__ float tile[32][33];
    const int h = blockIdx.z;
    const int c0 = blockIdx.y*32, w0 = blockIdx.x*32;
    const int lx = threadIdx.x & 31, ly = threadIdx.x >> 5;
    #pragma unroll
    for (int i=0;i<4;i++){
        int w = w0 + ly + i*8;
        float v = XH[(size_t)w*16384 + h*128 + c0 + lx]
                + XW[(size_t)h*16384 + w*128 + c0 + lx];
        tile[ly+i*8][lx] = v;
    }
    __syncthreads();
    #pragma unroll
    for (int i=0;i<4;i++){
        int c = c0 + ly + i*8;
        FH[(size_t)c*16384 + h*128 + w0 + lx] = tile[lx][ly+i*8];
    }
}

// ---------------------------------------------------------------------------
extern "C" void kernel_launch(void* const* d_in, const int* in_sizes, int n_in,
                              void* d_out, int out_size, void* d_ws, size_t ws_size,
                              hipStream_t stream)
{
    const float* x        = (const float*)d_in[0];
    const float* enc1_w   = (const float*)d_in[1];
    const float* enc1_b   = (const float*)d_in[2];
    const float* enc2_w   = (const float*)d_in[3];
    const float* enc2_b   = (const float*)d_in[4];
    const float* m_in_w   = (const float*)d_in[5];
    const float* m_conv_w = (const float*)d_in[6];
    const float* m_conv_b = (const float*)d_in[7];
    const float* m_xproj_w= (const float*)d_in[8];
    const float* m_dt_w   = (const float*)d_in[9];
    const float* m_dt_b   = (const float*)d_in[10];
    const float* m_Alog   = (const float*)d_in[11];
    const float* m_D      = (const float*)d_in[12];
    const float* m_out_w  = (const float*)d_in[13];
    const float* fus_w    = (const float*)d_in[14];
    const float* fus_b    = (const float*)d_in[15];
    const float* pred1_w  = (const float*)d_in[16];
    const float* pred1_b  = (const float*)d_in[17];
    const float* pred2_w  = (const float*)d_in[18];
    const float* pred2_b  = (const float*)d_in[19];
    float* out = (float*)d_out;

    float* ws    = (float*)d_ws;
    float* FEATS = ws;                         // 2M floats
    float* XH    = ws +  2u*1024*1024;         // 2M
    float* XW    = ws +  4u*1024*1024;         // 2M
    float* XZ    = ws +  6u*1024*1024;         // 8M  [NTOK,512]
    float* U     = ws + 14u*1024*1024;         // 4M  [NTOK,256]
    float* PROJ  = ws + 18u*1024*1024;         // 640K [NTOK,40]
    // liveness-based aliases within XZ (dead outside the mamba stacks):
    float* T0 = XZ;                  // conv1 output
    float* FH = XZ;                  // feats_h + feats_w
    float* G1 = XZ + 2u*1024*1024;   // fus conv output
    float* G2 = XZ + 4u*1024*1024;   // pred1 output
    // pre-split conv weights (bf16 hi/lo, 147456 ushorts each):
    // enc2: at ws+10M floats (dead region pre-mamba; overwritten later - ok)
    unsigned short* EHI = (unsigned short*)(ws + 10u*1024*1024);
    unsigned short* ELO = EHI + 147456;
    // fus/pred1: at ws+12M floats (dead post-mamba; XZ tail unused by decoder)
    unsigned short* FHI = (unsigned short*)(ws + 12u*1024*1024);
    unsigned short* FLO = FHI + 147456;
    unsigned short* PHI = FLO + 147456;
    unsigned short* PLO = PHI + 147456;

    const dim3 cmgrid(8, 32, 2);   // conv_mfma: 512 blocks

    // encoder
    conv3x3_kernel<true ><<<dim3(2,8,16), 256, 0, stream>>>(x, enc1_w, enc1_b, T0, 1, 128);
    wsplit_kernel<<<576, 256, 0, stream>>>(enc2_w, EHI, ELO);
    conv_mfma_kernel<false><<<cmgrid, 256, 0, stream>>>(T0, EHI, ELO, enc2_b, FEATS);

    // layouts for the two scan directions
    transpose_cw_kernel<<<dim3(4,4,128), 256, 0, stream>>>(FEATS, XH, 16384, 128); // [w,h,c]
    transpose_cw_kernel<<<dim3(4,4,128), 256, 0, stream>>>(FEATS, XW, 128, 16384); // [h,w,c]

    for (int pass = 0; pass < 2; pass++){
        float* Xact = pass ? XW : XH;
        for (int l = 0; l < 3; l++){
            gemm_mfma_kernel<<<dim3(256,8), 256, 0, stream>>>(Xact, m_in_w + (size_t)l*512*128, XZ, NTOK, 512, 128);
            conv1d_silu_kernel<<<NTOK, 256, 0, stream>>>(XZ, m_conv_w + (size_t)l*256*4, m_conv_b + (size_t)l*256, U);
            gemm_mfma_kernel<<<dim3(256,1), 256, 0, stream>>>(U, m_xproj_w + (size_t)l*40*256, PROJ, NTOK, 40, 256);
            scan_fused_kernel<<<dim3(4,128), 64, 0, stream>>>(XZ, U, PROJ,
                m_dt_w + (size_t)l*256*8, m_dt_b + (size_t)l*256,
                m_Alog + (size_t)l*256*16, m_D + (size_t)l*256);
            gemm_mfma_kernel<<<dim3(256,2), 256, 0, stream>>>(U, m_out_w + (size_t)l*128*256, Xact, NTOK, 128, 256);
        }
    }

    fuse_transpose_kernel<<<dim3(4,4,128), 256, 0, stream>>>(XH, XW, FH);

    // decoder
    wsplit_kernel<<<576, 256, 0, stream>>>(fus_w, FHI, FLO);
    conv_mfma_kernel<false><<<cmgrid, 256, 0, stream>>>(FH, FHI, FLO, fus_b, G1);
    wsplit_kernel<<<576, 256, 0, stream>>>(pred1_w, PHI, PLO);
    conv_mfma_kernel<true ><<<cmgrid, 256, 0, stream>>>(G1, PHI, PLO, pred1_b, G2);
    conv3x3_co1_kernel<<<64, 256, 0, stream>>>(G2, pred2_w, pred2_b, out, 128);
}